// Round 5
// baseline (489.576 us; speedup 1.0000x reference)
//
#include <hip/hip_runtime.h>

#define S_LEN 2048
#define DH 64

typedef float f32x4 __attribute__((ext_vector_type(4)));
typedef __bf16 bf16x8 __attribute__((ext_vector_type(8)));
typedef unsigned u32x2v __attribute__((ext_vector_type(2)));

#define MFMA16(A, B, C) __builtin_amdgcn_mfma_f32_16x16x32_bf16(A, B, C, 0, 0, 0)

#ifdef __has_builtin
#if __has_builtin(__builtin_amdgcn_permlane16_swap) && __has_builtin(__builtin_amdgcn_permlane32_swap)
#define HAVE_PLSWAP 1
#endif
#if __has_builtin(__builtin_amdgcn_global_load_lds)
#define HAVE_GLDS 1
#endif
#if __has_builtin(__builtin_amdgcn_s_setprio)
#define SETPRIO(x) __builtin_amdgcn_s_setprio(x)
#endif
#endif
#ifndef HAVE_PLSWAP
#define HAVE_PLSWAP 0
#endif
#ifndef HAVE_GLDS
#define HAVE_GLDS 0
#endif
#ifndef SETPRIO
#define SETPRIO(x)
#endif

__device__ __forceinline__ unsigned short f2bf(float f) {
    unsigned u = __builtin_bit_cast(unsigned, f);
    u += 0x7fffu + ((u >> 16) & 1u);
    return (unsigned short)(u >> 16);
}

__device__ __forceinline__ uint4 pack8(const float* s) {
    unsigned short h[8];
#pragma unroll
    for (int i = 0; i < 8; ++i) h[i] = f2bf(s[i]);
    return *(const uint4*)h;
}

// truncating pack (1 VALU op); bias cancels in O = (P V)/(P 1)
__device__ __forceinline__ unsigned pack_tr(float a, float b) {
    return __builtin_amdgcn_perm(__builtin_bit_cast(unsigned, b),
                                 __builtin_bit_cast(unsigned, a), 0x07060302u);
}

__device__ __forceinline__ bf16x8 ld128(const unsigned short* p) {
    return __builtin_bit_cast(bf16x8, *(const uint4*)p);
}

__device__ __forceinline__ bf16x8 ones8() {
    uint4 ou; ou.x = 0x3F803F80u; ou.y = ou.x; ou.z = ou.x; ou.w = ou.x;
    return __builtin_bit_cast(bf16x8, ou);
}

// ---- cross-lane P redistribution: C-layout (4 keys/lane) -> A-frag --------
__device__ __forceinline__ void pl32pair(unsigned& x, unsigned& y) {
#if HAVE_PLSWAP
    u32x2v r = __builtin_amdgcn_permlane32_swap(x, y, false, false);
    x = r[0]; y = r[1];
#else
    unsigned sx = __shfl_xor(x, 32, 64);
    unsigned sy = __shfl_xor(y, 32, 64);
    const bool hi = (threadIdx.x & 32) != 0;
    unsigned nx = hi ? sy : x;
    unsigned ny = hi ? y : sx;
    x = nx; y = ny;
#endif
}

__device__ __forceinline__ void pl16pair(unsigned& x, unsigned& y) {
#if HAVE_PLSWAP
    u32x2v r = __builtin_amdgcn_permlane16_swap(x, y, false, false);
    x = r[0]; y = r[1];
#else
    unsigned sx = __shfl_xor(x, 16, 64);
    unsigned sy = __shfl_xor(y, 16, 64);
    const bool odd = (threadIdx.x & 16) != 0;
    unsigned nx = odd ? sy : x;
    unsigned ny = odd ? y : sx;
    x = nx; y = ny;
#endif
}

// Inputs (lane quad q, col c): A0 = keys {4q,4q+1} of mt=2h, B0 = {4q+2,4q+3},
// A1/B1 same for mt=2h+1. Output: A-frag, lane q' holding keys q'*8..q'*8+7
// (relative to the 32-key half) of row c.
__device__ __forceinline__ bf16x8 frag_from(unsigned A0, unsigned B0,
                                            unsigned A1, unsigned B1) {
    pl32pair(A0, A1);
    pl16pair(A0, A1);   // A0=w0  A1=w2
    pl32pair(B0, B1);
    pl16pair(B0, B1);   // B0=w1  B1=w3
    uint4 u; u.x = A0; u.y = B0; u.z = A1; u.w = B1;
    return __builtin_bit_cast(bf16x8, u);
}

// ---- async global->LDS (16B/lane, linear dest = our exact layout) ---------
__device__ __forceinline__ void glds16(const uint4* g, unsigned short* l) {
#if HAVE_GLDS
    __builtin_amdgcn_global_load_lds(
        (const __attribute__((address_space(1))) uint4*)g,
        (__attribute__((address_space(3))) uint4*)l, 16, 0, 0);
#else
    *(uint4*)l = *g;
#endif
}

// ---- in-kernel K/V image conversion (same output bytes as old prep_kv) ----
__device__ __forceinline__ void conv_k(const float* __restrict__ k,
                                       uint4* __restrict__ kimg,
                                       int hb, int t) {
    const int r = t >> 3, b = t & 7;
    const int srcblk = b ^ (r & 7);
    const float* src = k + ((size_t)hb * 32 + r) * 64 + srcblk * 8;
    float buf[8];
    *(float4*)&buf[0] = *(const float4*)src;
    *(float4*)&buf[4] = *(const float4*)(src + 4);
    kimg[(size_t)hb * 256 + t] = pack8(buf);
}

// caller must __syncthreads() between consecutive calls (tr reuse)
__device__ __forceinline__ void conv_v(const float* __restrict__ v,
                                       uint4* __restrict__ vimg,
                                       int hb, int t, unsigned short* tr) {
    const int r = t >> 3, cb = t & 7;
    const float* src = v + ((size_t)hb * 32 + r) * 64 + cb * 8;
    float buf[8];
    *(float4*)&buf[0] = *(const float4*)src;
    *(float4*)&buf[4] = *(const float4*)(src + 4);
#pragma unroll
    for (int i = 0; i < 8; ++i)
        tr[(cb * 8 + i) * 40 + r] = f2bf(buf[i]);
    __syncthreads();
    const int d = t >> 2, kb2 = t & 3;
    const int skb = kb2 ^ ((d >> 1) & 3);
    vimg[(size_t)hb * 256 + t] = *(const uint4*)&tr[d * 40 + skb * 8];
}

// ---------------- dual-strip body (phase 1): frags shared ------------------
// Strip A = hi rows (unmasked here), strip B = lo rows (MB: diagonal mask).
template <bool MB>
__device__ __forceinline__ void body2(
    const unsigned short* __restrict__ kt_, const unsigned short* __restrict__ vt_,
    const bf16x8* qA, const bf16x8* qB,
    f32x4 (&accA)[4], f32x4 (&accB)[4], f32x4& aclA, f32x4& aclB,
    int igB, int kb, int quad, int c)
{
    const int sw = c & 7;
    const bf16x8 ones = ones8();
    const int f0 = (quad ^ sw) << 3;
    const int f1 = ((quad | 4) ^ sw) << 3;
    bf16x8 pfA[2], pfB[2];
#pragma unroll
    for (int h = 0; h < 2; ++h) {
        unsigned pA[2][2], pB[2][2];
#pragma unroll
        for (int m = 0; m < 2; ++m) {
            const int mt = 2 * h + m;
            const unsigned short* kr = kt_ + (mt * 16 + c) * 64;
            bf16x8 k0 = ld128(kr + f0), k1 = ld128(kr + f1);
            {
                f32x4 s = (f32x4){0.f, 0.f, 0.f, 0.f};
                s = MFMA16(k0, qA[0], s);
                s = MFMA16(k1, qA[1], s);
                float p[4];
#pragma unroll
                for (int r = 0; r < 4; ++r) p[r] = __builtin_amdgcn_exp2f(s[r]);
                pA[m][0] = pack_tr(p[0], p[1]);
                pA[m][1] = pack_tr(p[2], p[3]);
            }
            {
                f32x4 s = (f32x4){0.f, 0.f, 0.f, 0.f};
                s = MFMA16(k0, qB[0], s);
                s = MFMA16(k1, qB[1], s);
                float p[4];
#pragma unroll
                for (int r = 0; r < 4; ++r) {
                    float e = __builtin_amdgcn_exp2f(s[r]);
                    if (MB) {
                        const int jg = kb + mt * 16 + quad * 4 + r;
                        e = (jg > igB) ? 0.f : e;
                    }
                    p[r] = e;
                }
                pB[m][0] = pack_tr(p[0], p[1]);
                pB[m][1] = pack_tr(p[2], p[3]);
            }
        }
        pfA[h] = frag_from(pA[0][0], pA[0][1], pA[1][0], pA[1][1]);
        aclA = MFMA16(pfA[h], ones, aclA);
        pfB[h] = frag_from(pB[0][0], pB[0][1], pB[1][0], pB[1][1]);
        aclB = MFMA16(pfB[h], ones, aclB);
    }
    const int vsw = (c >> 1) & 3;
#pragma unroll
    for (int dc = 0; dc < 4; ++dc) {
        const int vo = (dc * 16 + c) * 32 + ((quad ^ vsw) << 3);
        bf16x8 v0 = ld128(vt_ + vo), v1 = ld128(vt_ + vo + 2048);
        accA[dc] = MFMA16(pfA[0], v0, accA[dc]);
        accA[dc] = MFMA16(pfA[1], v1, accA[dc]);
        accB[dc] = MFMA16(pfB[0], v0, accB[dc]);
        accB[dc] = MFMA16(pfB[1], v1, accB[dc]);
    }
}

// ---------------- single-strip body (phase 2): one key-partial -------------
template <bool MASK>
__device__ __forceinline__ void body1(
    const unsigned short* __restrict__ kt_, const unsigned short* __restrict__ vt_,
    const bf16x8* qA, f32x4 (&acc)[4], f32x4& acl,
    int ig, int kb, int quad, int c)
{
    const int sw = c & 7;
    const bf16x8 ones = ones8();
    const int f0 = (quad ^ sw) << 3;
    const int f1 = ((quad | 4) ^ sw) << 3;
    bf16x8 pf[2];
#pragma unroll
    for (int h = 0; h < 2; ++h) {
        unsigned pA[2][2];
#pragma unroll
        for (int m = 0; m < 2; ++m) {
            const int mt = 2 * h + m;
            const unsigned short* kr = kt_ + (mt * 16 + c) * 64;
            bf16x8 k0 = ld128(kr + f0), k1 = ld128(kr + f1);
            f32x4 s = (f32x4){0.f, 0.f, 0.f, 0.f};
            s = MFMA16(k0, qA[0], s);
            s = MFMA16(k1, qA[1], s);
            float p[4];
#pragma unroll
            for (int r = 0; r < 4; ++r) {
                float e = __builtin_amdgcn_exp2f(s[r]);
                if (MASK) {
                    const int jg = kb + mt * 16 + quad * 4 + r;
                    e = (jg > ig) ? 0.f : e;
                }
                p[r] = e;
            }
            pA[m][0] = pack_tr(p[0], p[1]);
            pA[m][1] = pack_tr(p[2], p[3]);
        }
        pf[h] = frag_from(pA[0][0], pA[0][1], pA[1][0], pA[1][1]);
        acl = MFMA16(pf[h], ones, acl);
    }
    const int vsw = (c >> 1) & 3;
#pragma unroll
    for (int dc = 0; dc < 4; ++dc) {
        const int vo = (dc * 16 + c) * 32 + ((quad ^ vsw) << 3);
        bf16x8 v0 = ld128(vt_ + vo), v1 = ld128(vt_ + vo + 2048);
        acc[dc] = MFMA16(pf[0], v0, acc[dc]);
        acc[dc] = MFMA16(pf[1], v1, acc[dc]);
    }
}

__device__ __forceinline__ void write_strip(float* __restrict__ ob,
                                            const f32x4* acc, const f32x4 acl,
                                            int rowbase, int quad, int c) {
    float linv[4];
#pragma unroll
    for (int r = 0; r < 4; ++r) linv[r] = 1.0f / acl[r];
#pragma unroll
    for (int dc = 0; dc < 4; ++dc)
#pragma unroll
        for (int r = 0; r < 4; ++r) {
            const size_t idx =
                (size_t)(rowbase + quad * 4 + r) * DH + dc * 16 + c;
            ob[idx] = acc[dc][r] * linv[r];
        }
}

// ---------------- fused kernel: prep + per-head barrier + attention --------
// Grid 1024 = 64 heads x 16 ci-blocks. Each block first converts its 1/16
// share of head bh's K/V bf16 images into workspace (same bytes as the old
// prep_kv), release-fences, arrives at ctr[bh], builds Q frags while other
// blocks finish, acquire-spins to 16 arrivals, then runs the round-3 loop:
// jt = 0..ci dual strips (lo retires at diagonal), jt = ci+1..31-ci single
// hi strip alternating two key-partials, in-register merge. 1 barrier/tile,
// prefetch always issued one body ahead.
__global__ __launch_bounds__(256, 4) void fa_kernel(
    const float* __restrict__ q,
    const float* __restrict__ kglob,
    const float* __restrict__ vglob,
    uint4* __restrict__ kimg,
    uint4* __restrict__ vimg,
    int* __restrict__ ctr,
    float* __restrict__ out)
{
    __shared__ unsigned short kt[2][64 * 64];     // 2 x 8 KB
    __shared__ unsigned short vt[2][2 * 64 * 32]; // 2 x 8 KB

    const int tid  = threadIdx.x;
    const int lane = tid & 63;
    const int wave = tid >> 6;
    const int quad = lane >> 4;
    const int c    = lane & 15;

    const int bid = blockIdx.x;
    const int bh  = bid & 63;
    const int ci  = bid >> 6;                     // 0..15
    const int last = 31 - ci;
    const int hib = last * 64 + wave * 16;        // hi strip base row
    const int lob = ci * 64 + wave * 16;          // lo strip base row

    const size_t head_off = (size_t)bh * S_LEN * DH;

    // ---- prep phase: convert this block's share (4 K + 4 V half-tiles) ----
    {
        unsigned short* tr = &kt[0][0];           // 5120 B scratch overlay
        const int base = bh * 64 + ci * 4;
#pragma unroll
        for (int u = 0; u < 4; ++u) conv_k(kglob, kimg, base + u, tid);
#pragma unroll
        for (int u = 0; u < 4; ++u) {
            conv_v(vglob, vimg, base + u, tid, tr);
            __syncthreads();
        }
        __threadfence();                          // release image stores
        __syncthreads();
        if (tid == 0)
            __hip_atomic_fetch_add(&ctr[bh], 1, __ATOMIC_RELEASE,
                                   __HIP_MEMORY_SCOPE_AGENT);
    }

    // Q fragments: [0,1] = hi strip, [2,3] = lo strip (log2-domain pre-scale)
    // (independent of images -> overlaps other blocks' conversion)
    const float SCALE = 0.125f * 1.4426950408889634f;
    bf16x8 qf[4];
#pragma unroll
    for (int s = 0; s < 2; ++s) {
        const int base = s ? lob : hib;
        const float* qrow = q + head_off + (size_t)(base + c) * DH;
        float t0[8], t1[8];
#pragma unroll
        for (int i = 0; i < 8; ++i) t0[i] = qrow[quad * 8 + i] * SCALE;
#pragma unroll
        for (int i = 0; i < 8; ++i) t1[i] = qrow[32 + quad * 8 + i] * SCALE;
        qf[s * 2 + 0] = __builtin_bit_cast(bf16x8, pack8(t0));
        qf[s * 2 + 1] = __builtin_bit_cast(bf16x8, pack8(t1));
    }

    // ---- per-head barrier: wait for all 16 blocks of head bh ----
    if (tid == 0) {
        while (__hip_atomic_load(&ctr[bh], __ATOMIC_ACQUIRE,
                                 __HIP_MEMORY_SCOPE_AGENT) < 16)
            __builtin_amdgcn_s_sleep(2);
    }
    __syncthreads();
    __threadfence();                              // acquire side

    const uint4* kin = kimg + (size_t)bh * 16384;
    const uint4* vin = vimg + (size_t)bh * 16384;

    auto stage = [&](int jt, int b) {
        const uint4* kg = kin + jt * 512 + tid;
        const uint4* vg = vin + jt * 512 + tid;
        glds16(kg,       &kt[b][0] + (size_t)tid * 8);
        glds16(kg + 256, &kt[b][0] + (size_t)(tid + 256) * 8);
        glds16(vg,       &vt[b][0] + (size_t)tid * 8);
        glds16(vg + 256, &vt[b][0] + (size_t)(tid + 256) * 8);
    };

    stage(0, 0);

    f32x4 accA[4], accB[4];
#pragma unroll
    for (int dc = 0; dc < 4; ++dc) {
        accA[dc] = (f32x4){0.f, 0.f, 0.f, 0.f};
        accB[dc] = (f32x4){0.f, 0.f, 0.f, 0.f};
    }
    f32x4 aclA = (f32x4){0.f, 0.f, 0.f, 0.f};
    f32x4 aclB = (f32x4){0.f, 0.f, 0.f, 0.f};

    const int igA = hib + c;
    const int igB = lob + c;

    // ---- phase 1: jt = 0..ci, dual strips, shared frags ----
    int jt = 0;
    for (; jt <= ci; ++jt) {
        __syncthreads();                      // drains stage(jt)
        if (jt < last) stage(jt + 1, (jt + 1) & 1);
        const unsigned short* K = kt[jt & 1];
        const unsigned short* V = vt[jt & 1];
        SETPRIO(1);
        if (jt < ci)
            body2<false>(K, V, qf, qf + 2, accA, accB, aclA, aclB,
                         igB, jt * 64, quad, c);
        else
            body2<true>(K, V, qf, qf + 2, accA, accB, aclA, aclB,
                        igB, jt * 64, quad, c);
        SETPRIO(0);
    }

    // ---- retire lo strip; accB becomes the hi strip's second key-partial
    write_strip(out + head_off, accB, aclB, lob, quad, c);
#pragma unroll
    for (int dc = 0; dc < 4; ++dc) accB[dc] = (f32x4){0.f, 0.f, 0.f, 0.f};
    aclB = (f32x4){0.f, 0.f, 0.f, 0.f};

    // ---- phase 2: jt = ci+1..last, single strip, alternating partials ----
    for (; jt <= last; ++jt) {
        __syncthreads();                      // drains stage(jt)
        if (jt < last) stage(jt + 1, (jt + 1) & 1);
        const unsigned short* K = kt[jt & 1];
        const unsigned short* V = vt[jt & 1];
        const int kb = jt * 64;
        SETPRIO(1);
        if ((jt ^ ci) & 1) {
            if (jt == last) body1<true >(K, V, qf, accB, aclB, igA, kb, quad, c);
            else            body1<false>(K, V, qf, accB, aclB, igA, kb, quad, c);
        } else {
            if (jt == last) body1<true >(K, V, qf, accA, aclA, igA, kb, quad, c);
            else            body1<false>(K, V, qf, accA, aclA, igA, kb, quad, c);
        }
        SETPRIO(0);
    }

    // ---- merge key-partials in-register, final epilogue for hi strip
#pragma unroll
    for (int dc = 0; dc < 4; ++dc) accA[dc] += accB[dc];
    aclA += aclB;
    write_strip(out + head_off, accA, aclA, hib, quad, c);
}

// ---------------- fallback (self-contained, used if ws too small) ----------
#define KT_STRIDE 88
#define VT_STRIDE 36
__global__ __launch_bounds__(256) void fa_kernel_fb(
    const float* __restrict__ q, const float* __restrict__ k,
    const float* __restrict__ v, float* __restrict__ out)
{
    __shared__ unsigned short kts[32 * KT_STRIDE];
    __shared__ unsigned short vts[64 * VT_STRIDE];
    __shared__ unsigned short pts[4][16 * 40];
    const int tid = threadIdx.x, lane = tid & 63, wave = tid >> 6;
    const int quad = lane >> 4, c = lane & 15;
    const int bid = blockIdx.x, bh = bid & 63, qblk = 31 - (bid >> 6);
    const int qtile = qblk * 4 + wave, qbase = qtile * 16;
    const int my_diag = qtile >> 1, jt_last = (qblk * 4 + 3) >> 1;
    const size_t head_off = (size_t)bh * S_LEN * DH;
    const float* qrow = q + head_off + (size_t)(qbase + c) * DH;
    float qtmp[8];
#pragma unroll
    for (int i = 0; i < 8; ++i) qtmp[i] = qrow[quad * 8 + i];
    bf16x8 qf0 = __builtin_bit_cast(bf16x8, pack8(qtmp));
#pragma unroll
    for (int i = 0; i < 8; ++i) qtmp[i] = qrow[32 + quad * 8 + i];
    bf16x8 qf1 = __builtin_bit_cast(bf16x8, pack8(qtmp));
    f32x4 acc[4];
#pragma unroll
    for (int dc = 0; dc < 4; ++dc) acc[dc] = (f32x4){0.f, 0.f, 0.f, 0.f};
    float m_run = -1e30f, l_run = 0.f;
    const int ig = qbase + c;
    const int srow = tid >> 3, sdb = tid & 7;
    const int vcol = (((srow >> 3) ^ (sdb & 3)) << 3) | (srow & 7);
    const float LOG2E = 1.4426950408889634f;
    for (int jt = 0; jt <= jt_last; ++jt) {
        __syncthreads();
        {
            const size_t g = head_off + (size_t)(jt * 32 + srow) * DH + sdb * 8;
            float kbuf[8];
            *(float4*)&kbuf[0] = *(const float4*)(k + g);
            *(float4*)&kbuf[4] = *(const float4*)(k + g + 4);
            *(uint4*)&kts[srow * KT_STRIDE + sdb * 8] = pack8(kbuf);
            float vbuf[8];
            *(float4*)&vbuf[0] = *(const float4*)(v + g);
            *(float4*)&vbuf[4] = *(const float4*)(v + g + 4);
#pragma unroll
            for (int i = 0; i < 8; ++i)
                vts[(sdb * 8 + i) * VT_STRIDE + vcol] = f2bf(vbuf[i]);
        }
        __syncthreads();
        if (jt > my_diag) continue;
        f32x4 st[2];
#pragma unroll
        for (int mt = 0; mt < 2; ++mt) {
            const unsigned short* krow = &kts[(mt * 16 + c) * KT_STRIDE + quad * 8];
            bf16x8 ka0 = __builtin_bit_cast(bf16x8, *(const uint4*)krow);
            bf16x8 ka1 = __builtin_bit_cast(bf16x8, *(const uint4*)(krow + 32));
            f32x4 a = (f32x4){0.f, 0.f, 0.f, 0.f};
            a = MFMA16(ka0, qf0, a);
            a = MFMA16(ka1, qf1, a);
            st[mt] = a;
        }
        float tv[8];
#pragma unroll
        for (int mt = 0; mt < 2; ++mt)
#pragma unroll
            for (int r = 0; r < 4; ++r) {
                const int jg = jt * 32 + mt * 16 + quad * 4 + r;
                const float s = st[mt][r] * 0.125f;
                tv[mt * 4 + r] = (jg > ig) ? -1e30f : s;
            }
        float tm = tv[0];
#pragma unroll
        for (int i = 1; i < 8; ++i) tm = fmaxf(tm, tv[i]);
        tm = fmaxf(tm, __shfl_xor(tm, 16, 64));
        tm = fmaxf(tm, __shfl_xor(tm, 32, 64));
        const float m_new = fmaxf(m_run, tm);
        const float mb = m_new * LOG2E;
        float p[8], ps = 0.f;
#pragma unroll
        for (int i = 0; i < 8; ++i) {
            p[i] = __builtin_amdgcn_exp2f(tv[i] * LOG2E - mb);
            ps += p[i];
        }
        ps += __shfl_xor(ps, 16, 64);
        ps += __shfl_xor(ps, 32, 64);
        const float alpha = __builtin_amdgcn_exp2f((m_run - m_new) * LOG2E);
        l_run = l_run * alpha + ps;
        m_run = m_new;
        unsigned short* pwf = pts[wave];
#pragma unroll
        for (int mt = 0; mt < 2; ++mt)
#pragma unroll
            for (int r = 0; r < 4; ++r)
                pwf[c * 40 + mt * 16 + quad * 4 + r] = f2bf(p[mt * 4 + r]);
        float ar[4];
#pragma unroll
        for (int r = 0; r < 4; ++r)
            ar[r] = __shfl(alpha, (quad << 4) + quad * 4 + r, 64);
#pragma unroll
        for (int dc = 0; dc < 4; ++dc)
#pragma unroll
            for (int r = 0; r < 4; ++r) acc[dc][r] *= ar[r];
        bf16x8 pf = __builtin_bit_cast(bf16x8, *(const uint4*)&pwf[c * 40 + quad * 8]);
#pragma unroll
        for (int dc = 0; dc < 4; ++dc) {
            const int vrow = dc * 16 + c;
            const int blk = quad ^ ((vrow >> 3) & 3);
            const unsigned short* vp = &vts[vrow * VT_STRIDE + blk * 8];
            uint2 a0 = *(const uint2*)vp;
            uint2 a1 = *(const uint2*)(vp + 4);
            uint4 u; u.x = a0.x; u.y = a0.y; u.z = a1.x; u.w = a1.y;
            bf16x8 vf = __builtin_bit_cast(bf16x8, u);
            acc[dc] = MFMA16(pf, vf, acc[dc]);
        }
    }
    float linv[4];
#pragma unroll
    for (int r = 0; r < 4; ++r) {
        const float lr = __shfl(l_run, (quad << 4) + quad * 4 + r, 64);
        linv[r] = 1.0f / lr;
    }
    float* ob = out + head_off;
#pragma unroll
    for (int dc = 0; dc < 4; ++dc)
#pragma unroll
        for (int r = 0; r < 4; ++r) {
            const size_t idx = (size_t)(qbase + quad * 4 + r) * DH + dc * 16 + c;
            ob[idx] = acc[dc][r] * linv[r];
        }
}

extern "C" void kernel_launch(void* const* d_in, const int* in_sizes, int n_in,
                              void* d_out, int out_size, void* d_ws, size_t ws_size,
                              hipStream_t stream) {
    const float* q = (const float*)d_in[0];
    const float* k = (const float*)d_in[1];
    const float* v = (const float*)d_in[2];
    float* o = (float*)d_out;
    const size_t img_bytes = (size_t)2 * 64 * 64 * 4096;  // K + V images
    const size_t need = img_bytes + 256;                  // + head counters
    if (ws_size >= need) {
        uint4* kimg = (uint4*)d_ws;
        uint4* vimg = kimg + (size_t)64 * 64 * 256;
        int* ctr = (int*)((char*)d_ws + img_bytes);
        hipMemsetAsync(ctr, 0, 256, stream);
        hipLaunchKernelGGL(fa_kernel, dim3(1024), dim3(256), 0, stream,
                           q, k, v, kimg, vimg, ctr, o);
    } else {
        hipLaunchKernelGGL(fa_kernel_fb, dim3(2048), dim3(256), 0, stream, q, k, v, o);
    }
}

// Round 6
// 410.852 us; speedup vs baseline: 1.1916x; 1.1916x over previous
//
#include <hip/hip_runtime.h>
#include <hip/hip_cooperative_groups.h>

namespace cg = cooperative_groups;

#define S_LEN 2048
#define DH 64

typedef float f32x4 __attribute__((ext_vector_type(4)));
typedef __bf16 bf16x8 __attribute__((ext_vector_type(8)));
typedef unsigned u32x2v __attribute__((ext_vector_type(2)));

#define MFMA16(A, B, C) __builtin_amdgcn_mfma_f32_16x16x32_bf16(A, B, C, 0, 0, 0)

#ifdef __has_builtin
#if __has_builtin(__builtin_amdgcn_permlane16_swap) && __has_builtin(__builtin_amdgcn_permlane32_swap)
#define HAVE_PLSWAP 1
#endif
#if __has_builtin(__builtin_amdgcn_global_load_lds)
#define HAVE_GLDS 1
#endif
#if __has_builtin(__builtin_amdgcn_s_setprio)
#define SETPRIO(x) __builtin_amdgcn_s_setprio(x)
#endif
#endif
#ifndef HAVE_PLSWAP
#define HAVE_PLSWAP 0
#endif
#ifndef HAVE_GLDS
#define HAVE_GLDS 0
#endif
#ifndef SETPRIO
#define SETPRIO(x)
#endif

__device__ __forceinline__ unsigned short f2bf(float f) {
    unsigned u = __builtin_bit_cast(unsigned, f);
    u += 0x7fffu + ((u >> 16) & 1u);
    return (unsigned short)(u >> 16);
}

__device__ __forceinline__ uint4 pack8(const float* s) {
    unsigned short h[8];
#pragma unroll
    for (int i = 0; i < 8; ++i) h[i] = f2bf(s[i]);
    return *(const uint4*)h;
}

// truncating pack (1 VALU op); bias cancels in O = (P V)/(P 1)
__device__ __forceinline__ unsigned pack_tr(float a, float b) {
    return __builtin_amdgcn_perm(__builtin_bit_cast(unsigned, b),
                                 __builtin_bit_cast(unsigned, a), 0x07060302u);
}

__device__ __forceinline__ bf16x8 ld128(const unsigned short* p) {
    return __builtin_bit_cast(bf16x8, *(const uint4*)p);
}

__device__ __forceinline__ bf16x8 ones8() {
    uint4 ou; ou.x = 0x3F803F80u; ou.y = ou.x; ou.z = ou.x; ou.w = ou.x;
    return __builtin_bit_cast(bf16x8, ou);
}

// ---- cross-lane P redistribution: C-layout (4 keys/lane) -> A-frag --------
__device__ __forceinline__ void pl32pair(unsigned& x, unsigned& y) {
#if HAVE_PLSWAP
    u32x2v r = __builtin_amdgcn_permlane32_swap(x, y, false, false);
    x = r[0]; y = r[1];
#else
    unsigned sx = __shfl_xor(x, 32, 64);
    unsigned sy = __shfl_xor(y, 32, 64);
    const bool hi = (threadIdx.x & 32) != 0;
    unsigned nx = hi ? sy : x;
    unsigned ny = hi ? y : sx;
    x = nx; y = ny;
#endif
}

__device__ __forceinline__ void pl16pair(unsigned& x, unsigned& y) {
#if HAVE_PLSWAP
    u32x2v r = __builtin_amdgcn_permlane16_swap(x, y, false, false);
    x = r[0]; y = r[1];
#else
    unsigned sx = __shfl_xor(x, 16, 64);
    unsigned sy = __shfl_xor(y, 16, 64);
    const bool odd = (threadIdx.x & 16) != 0;
    unsigned nx = odd ? sy : x;
    unsigned ny = odd ? y : sx;
    x = nx; y = ny;
#endif
}

// Inputs (lane quad q, col c): A0 = keys {4q,4q+1} of mt=2h, B0 = {4q+2,4q+3},
// A1/B1 same for mt=2h+1. Output: A-frag, lane q' holding keys q'*8..q'*8+7
// (relative to the 32-key half) of row c.
__device__ __forceinline__ bf16x8 frag_from(unsigned A0, unsigned B0,
                                            unsigned A1, unsigned B1) {
    pl32pair(A0, A1);
    pl16pair(A0, A1);   // A0=w0  A1=w2
    pl32pair(B0, B1);
    pl16pair(B0, B1);   // B0=w1  B1=w3
    uint4 u; u.x = A0; u.y = B0; u.z = A1; u.w = B1;
    return __builtin_bit_cast(bf16x8, u);
}

// ---- async global->LDS (16B/lane, linear dest = our exact layout) ---------
__device__ __forceinline__ void glds16(const uint4* g, unsigned short* l) {
#if HAVE_GLDS
    __builtin_amdgcn_global_load_lds(
        (const __attribute__((address_space(1))) uint4*)g,
        (__attribute__((address_space(3))) uint4*)l, 16, 0, 0);
#else
    *(uint4*)l = *g;
#endif
}

// ---- K/V image conversion helpers (chunk = 32 rows of one head) -----------
// K: linear bf16 pack with pre-swizzled source columns.
__device__ __forceinline__ void conv_k(const float* __restrict__ k,
                                       uint4* __restrict__ kimg,
                                       int hb, int t) {
    const int r = t >> 3, b = t & 7;
    const int srcblk = b ^ (r & 7);
    const float* src = k + ((size_t)hb * 32 + r) * 64 + srcblk * 8;
    float buf[8];
    *(float4*)&buf[0] = *(const float4*)src;
    *(float4*)&buf[4] = *(const float4*)(src + 4);
    kimg[(size_t)hb * 256 + t] = pack8(buf);
}

// V: LDS transpose with XOR row-group swizzle (write conflicts 16->4 way);
// reads invert it, so emitted vimg bytes are identical to the unswizzled
// version (verified round 4). Caller syncs between consecutive calls.
__device__ __forceinline__ void conv_v(const float* __restrict__ v,
                                       uint4* __restrict__ vimg,
                                       int hb, int t, unsigned short* tr) {
    const int r = t >> 3, cb = t & 7;
    const float* src = v + ((size_t)hb * 32 + r) * 64 + cb * 8;
    float buf[8];
    *(float4*)&buf[0] = *(const float4*)src;
    *(float4*)&buf[4] = *(const float4*)(src + 4);
    const int rswz = (((r >> 3) ^ cb) & 3) * 8 + (r & 7);
#pragma unroll
    for (int i = 0; i < 8; ++i)
        tr[(cb * 8 + i) * 40 + rswz] = f2bf(buf[i]);
    __syncthreads();
    const int d = t >> 2, kb2 = t & 3;
    const int skb = kb2 ^ ((d >> 1) & 3);
    const int sloc = skb ^ ((d >> 3) & 3);
    vimg[(size_t)hb * 256 + t] = *(const uint4*)&tr[d * 40 + sloc * 8];
}

// ---------------- standalone pre-pass (fallback path) ----------------------
__global__ __launch_bounds__(256) void prep_kv(const float* __restrict__ k,
                                               const float* __restrict__ v,
                                               uint4* __restrict__ kimg,
                                               uint4* __restrict__ vimg) {
    __shared__ unsigned short tr[64 * 40];
    const int bid = blockIdx.x;
    const int t = threadIdx.x;
    if (bid < 4096) {
        conv_k(k, kimg, bid, t);
    } else {
        conv_v(v, vimg, bid - 4096, t, tr);
    }
}

// ---------------- dual-strip body (phase 1): frags shared ------------------
// Strip A = hi rows (unmasked here), strip B = lo rows (MB: diagonal mask).
template <bool MB>
__device__ __forceinline__ void body2(
    const unsigned short* __restrict__ kt_, const unsigned short* __restrict__ vt_,
    const bf16x8* qA, const bf16x8* qB,
    f32x4 (&accA)[4], f32x4 (&accB)[4], f32x4& aclA, f32x4& aclB,
    int igB, int kb, int quad, int c)
{
    const int sw = c & 7;
    const bf16x8 ones = ones8();
    const int f0 = (quad ^ sw) << 3;
    const int f1 = ((quad | 4) ^ sw) << 3;
    bf16x8 pfA[2], pfB[2];
#pragma unroll
    for (int h = 0; h < 2; ++h) {
        unsigned pA[2][2], pB[2][2];
#pragma unroll
        for (int m = 0; m < 2; ++m) {
            const int mt = 2 * h + m;
            const unsigned short* kr = kt_ + (mt * 16 + c) * 64;
            bf16x8 k0 = ld128(kr + f0), k1 = ld128(kr + f1);
            {
                f32x4 s = (f32x4){0.f, 0.f, 0.f, 0.f};
                s = MFMA16(k0, qA[0], s);
                s = MFMA16(k1, qA[1], s);
                float p[4];
#pragma unroll
                for (int r = 0; r < 4; ++r) p[r] = __builtin_amdgcn_exp2f(s[r]);
                pA[m][0] = pack_tr(p[0], p[1]);
                pA[m][1] = pack_tr(p[2], p[3]);
            }
            {
                f32x4 s = (f32x4){0.f, 0.f, 0.f, 0.f};
                s = MFMA16(k0, qB[0], s);
                s = MFMA16(k1, qB[1], s);
                float p[4];
#pragma unroll
                for (int r = 0; r < 4; ++r) {
                    float e = __builtin_amdgcn_exp2f(s[r]);
                    if (MB) {
                        const int jg = kb + mt * 16 + quad * 4 + r;
                        e = (jg > igB) ? 0.f : e;
                    }
                    p[r] = e;
                }
                pB[m][0] = pack_tr(p[0], p[1]);
                pB[m][1] = pack_tr(p[2], p[3]);
            }
        }
        pfA[h] = frag_from(pA[0][0], pA[0][1], pA[1][0], pA[1][1]);
        aclA = MFMA16(pfA[h], ones, aclA);
        pfB[h] = frag_from(pB[0][0], pB[0][1], pB[1][0], pB[1][1]);
        aclB = MFMA16(pfB[h], ones, aclB);
    }
    const int vsw = (c >> 1) & 3;
#pragma unroll
    for (int dc = 0; dc < 4; ++dc) {
        const int vo = (dc * 16 + c) * 32 + ((quad ^ vsw) << 3);
        bf16x8 v0 = ld128(vt_ + vo), v1 = ld128(vt_ + vo + 2048);
        accA[dc] = MFMA16(pfA[0], v0, accA[dc]);
        accA[dc] = MFMA16(pfA[1], v1, accA[dc]);
        accB[dc] = MFMA16(pfB[0], v0, accB[dc]);
        accB[dc] = MFMA16(pfB[1], v1, accB[dc]);
    }
}

// ---------------- single-strip body (phase 2): one key-partial -------------
template <bool MASK>
__device__ __forceinline__ void body1(
    const unsigned short* __restrict__ kt_, const unsigned short* __restrict__ vt_,
    const bf16x8* qA, f32x4 (&acc)[4], f32x4& acl,
    int ig, int kb, int quad, int c)
{
    const int sw = c & 7;
    const bf16x8 ones = ones8();
    const int f0 = (quad ^ sw) << 3;
    const int f1 = ((quad | 4) ^ sw) << 3;
    bf16x8 pf[2];
#pragma unroll
    for (int h = 0; h < 2; ++h) {
        unsigned pA[2][2];
#pragma unroll
        for (int m = 0; m < 2; ++m) {
            const int mt = 2 * h + m;
            const unsigned short* kr = kt_ + (mt * 16 + c) * 64;
            bf16x8 k0 = ld128(kr + f0), k1 = ld128(kr + f1);
            f32x4 s = (f32x4){0.f, 0.f, 0.f, 0.f};
            s = MFMA16(k0, qA[0], s);
            s = MFMA16(k1, qA[1], s);
            float p[4];
#pragma unroll
            for (int r = 0; r < 4; ++r) {
                float e = __builtin_amdgcn_exp2f(s[r]);
                if (MASK) {
                    const int jg = kb + mt * 16 + quad * 4 + r;
                    e = (jg > ig) ? 0.f : e;
                }
                p[r] = e;
            }
            pA[m][0] = pack_tr(p[0], p[1]);
            pA[m][1] = pack_tr(p[2], p[3]);
        }
        pf[h] = frag_from(pA[0][0], pA[0][1], pA[1][0], pA[1][1]);
        acl = MFMA16(pf[h], ones, acl);
    }
    const int vsw = (c >> 1) & 3;
#pragma unroll
    for (int dc = 0; dc < 4; ++dc) {
        const int vo = (dc * 16 + c) * 32 + ((quad ^ vsw) << 3);
        bf16x8 v0 = ld128(vt_ + vo), v1 = ld128(vt_ + vo + 2048);
        acc[dc] = MFMA16(pf[0], v0, acc[dc]);
        acc[dc] = MFMA16(pf[1], v1, acc[dc]);
    }
}

__device__ __forceinline__ void write_strip(float* __restrict__ ob,
                                            const f32x4* acc, const f32x4 acl,
                                            int rowbase, int quad, int c) {
    float linv[4];
#pragma unroll
    for (int r = 0; r < 4; ++r) linv[r] = 1.0f / acl[r];
#pragma unroll
    for (int dc = 0; dc < 4; ++dc)
#pragma unroll
        for (int r = 0; r < 4; ++r) {
            const size_t idx =
                (size_t)(rowbase + quad * 4 + r) * DH + dc * 16 + c;
            ob[idx] = acc[dc][r] * linv[r];
        }
}

// ---------------- main attention loop (round-3 verified structure) ---------
// Block ci (0..15) owns 64-row chunk ci (lo) + chunk 31-ci (hi). Each wave
// owns a 16-row strip of each. jt = 0..ci: both strips vs the staged tile
// (frags shared); lo strip masked+retired at jt==ci. jt = ci+1..31-ci: one
// key-partial of the hi strip per tile, target alternating accA/accB by
// parity (static call sites); merged in-register at the end. Every tile:
// exactly one __syncthreads, and its stage was issued one full body earlier.
__device__ __forceinline__ void fa_main(
    const float* __restrict__ q,
    const uint4* __restrict__ kin,
    const uint4* __restrict__ vin,
    float* __restrict__ out,
    size_t head_off, int ci)
{
    __shared__ unsigned short kt[2][64 * 64];     // 2 x 8 KB
    __shared__ unsigned short vt[2][2 * 64 * 32]; // 2 x 8 KB

    const int tid  = threadIdx.x;
    const int lane = tid & 63;
    const int wave = tid >> 6;
    const int quad = lane >> 4;
    const int c    = lane & 15;

    const int last = 31 - ci;
    const int hib = last * 64 + wave * 16;        // hi strip base row
    const int lob = ci * 64 + wave * 16;          // lo strip base row

    auto stage = [&](int jt, int b) {
        const uint4* kg = kin + jt * 512 + tid;
        const uint4* vg = vin + jt * 512 + tid;
        glds16(kg,       &kt[b][0] + (size_t)tid * 8);
        glds16(kg + 256, &kt[b][0] + (size_t)(tid + 256) * 8);
        glds16(vg,       &vt[b][0] + (size_t)tid * 8);
        glds16(vg + 256, &vt[b][0] + (size_t)(tid + 256) * 8);
    };

    stage(0, 0);

    // Q fragments: [0,1] = hi strip, [2,3] = lo strip (log2-domain pre-scale)
    const float SCALE = 0.125f * 1.4426950408889634f;
    bf16x8 qf[4];
#pragma unroll
    for (int s = 0; s < 2; ++s) {
        const int base = s ? lob : hib;
        const float* qrow = q + head_off + (size_t)(base + c) * DH;
        float t0[8], t1[8];
#pragma unroll
        for (int i = 0; i < 8; ++i) t0[i] = qrow[quad * 8 + i] * SCALE;
#pragma unroll
        for (int i = 0; i < 8; ++i) t1[i] = qrow[32 + quad * 8 + i] * SCALE;
        qf[s * 2 + 0] = __builtin_bit_cast(bf16x8, pack8(t0));
        qf[s * 2 + 1] = __builtin_bit_cast(bf16x8, pack8(t1));
    }

    f32x4 accA[4], accB[4];
#pragma unroll
    for (int dc = 0; dc < 4; ++dc) {
        accA[dc] = (f32x4){0.f, 0.f, 0.f, 0.f};
        accB[dc] = (f32x4){0.f, 0.f, 0.f, 0.f};
    }
    f32x4 aclA = (f32x4){0.f, 0.f, 0.f, 0.f};
    f32x4 aclB = (f32x4){0.f, 0.f, 0.f, 0.f};

    const int igA = hib + c;
    const int igB = lob + c;

    // ---- phase 1: jt = 0..ci, dual strips, shared frags ----
    int jt = 0;
    for (; jt <= ci; ++jt) {
        __syncthreads();                      // drains stage(jt)
        if (jt < last) stage(jt + 1, (jt + 1) & 1);
        const unsigned short* K = kt[jt & 1];
        const unsigned short* V = vt[jt & 1];
        SETPRIO(1);
        if (jt < ci)
            body2<false>(K, V, qf, qf + 2, accA, accB, aclA, aclB,
                         igB, jt * 64, quad, c);
        else
            body2<true>(K, V, qf, qf + 2, accA, accB, aclA, aclB,
                        igB, jt * 64, quad, c);
        SETPRIO(0);
    }

    // ---- retire lo strip; accB becomes the hi strip's second key-partial
    write_strip(out + head_off, accB, aclB, lob, quad, c);
#pragma unroll
    for (int dc = 0; dc < 4; ++dc) accB[dc] = (f32x4){0.f, 0.f, 0.f, 0.f};
    aclB = (f32x4){0.f, 0.f, 0.f, 0.f};

    // ---- phase 2: jt = ci+1..last, single strip, alternating partials ----
    for (; jt <= last; ++jt) {
        __syncthreads();                      // drains stage(jt)
        if (jt < last) stage(jt + 1, (jt + 1) & 1);
        const unsigned short* K = kt[jt & 1];
        const unsigned short* V = vt[jt & 1];
        const int kb = jt * 64;
        SETPRIO(1);
        if ((jt ^ ci) & 1) {
            if (jt == last) body1<true >(K, V, qf, accB, aclB, igA, kb, quad, c);
            else            body1<false>(K, V, qf, accB, aclB, igA, kb, quad, c);
        } else {
            if (jt == last) body1<true >(K, V, qf, accA, aclA, igA, kb, quad, c);
            else            body1<false>(K, V, qf, accA, aclA, igA, kb, quad, c);
        }
        SETPRIO(0);
    }

    // ---- merge key-partials in-register, final epilogue for hi strip
#pragma unroll
    for (int dc = 0; dc < 4; ++dc) accA[dc] += accB[dc];
    aclA += aclB;
    write_strip(out + head_off, accA, aclA, hib, quad, c);
}

// ---------------- standalone attention kernel (fallback path) --------------
__global__ __launch_bounds__(256, 4) void fa_kernel(
    const float* __restrict__ q,
    const uint4* __restrict__ kimg,
    const uint4* __restrict__ vimg,
    float* __restrict__ out)
{
    const int bid = blockIdx.x;
    const int bh  = bid & 63;
    const int ci  = bid >> 6;
    const size_t head_off = (size_t)bh * S_LEN * DH;
    fa_main(q, kimg + (size_t)bh * 16384, vimg + (size_t)bh * 16384,
            out, head_off, ci);
}

// ---------------- fused cooperative kernel: prep + grid.sync + attention ---
// Grid 1024 = 64 heads x 16 ci-blocks (fits co-resident: 4-5 blocks/CU by
// LDS). Each block converts its 1/16 share of its head's K/V images (chunks
// bh*64+ci*4 .. +3 for K and V), fences, grid-syncs (runtime-managed, no
// user-atomic spin — round-5's hand barrier caused an LLC poll storm), then
// runs the same fa_main as the fallback path.
__global__ __launch_bounds__(256, 4) void fa_fused(
    const float* __restrict__ q,
    const float* __restrict__ kglob,
    const float* __restrict__ vglob,
    uint4* __restrict__ kimg,
    uint4* __restrict__ vimg,
    float* __restrict__ out)
{
    __shared__ unsigned short tr[64 * 40];        // conv_v scratch (5 KB)

    const int tid = threadIdx.x;
    const int bid = blockIdx.x;
    const int bh  = bid & 63;
    const int ci  = bid >> 6;
    const size_t head_off = (size_t)bh * S_LEN * DH;

    {
        const int base = bh * 64 + ci * 4;
#pragma unroll
        for (int u = 0; u < 4; ++u) conv_k(kglob, kimg, base + u, tid);
#pragma unroll
        for (int u = 0; u < 4; ++u) {
            conv_v(vglob, vimg, base + u, tid, tr);
            __syncthreads();                  // tr reuse
        }
        __threadfence();                      // release image stores
    }

    cg::this_grid().sync();                   // all images visible everywhere

    fa_main(q, kimg + (size_t)bh * 16384, vimg + (size_t)bh * 16384,
            out, head_off, ci);
}

// ---------------- fallback (self-contained, used if ws too small) ----------
#define KT_STRIDE 88
#define VT_STRIDE 36
__global__ __launch_bounds__(256) void fa_kernel_fb(
    const float* __restrict__ q, const float* __restrict__ k,
    const float* __restrict__ v, float* __restrict__ out)
{
    __shared__ unsigned short kts[32 * KT_STRIDE];
    __shared__ unsigned short vts[64 * VT_STRIDE];
    __shared__ unsigned short pts[4][16 * 40];
    const int tid = threadIdx.x, lane = tid & 63, wave = tid >> 6;
    const int quad = lane >> 4, c = lane & 15;
    const int bid = blockIdx.x, bh = bid & 63, qblk = 31 - (bid >> 6);
    const int qtile = qblk * 4 + wave, qbase = qtile * 16;
    const int my_diag = qtile >> 1, jt_last = (qblk * 4 + 3) >> 1;
    const size_t head_off = (size_t)bh * S_LEN * DH;
    const float* qrow = q + head_off + (size_t)(qbase + c) * DH;
    float qtmp[8];
#pragma unroll
    for (int i = 0; i < 8; ++i) qtmp[i] = qrow[quad * 8 + i];
    bf16x8 qf0 = __builtin_bit_cast(bf16x8, pack8(qtmp));
#pragma unroll
    for (int i = 0; i < 8; ++i) qtmp[i] = qrow[32 + quad * 8 + i];
    bf16x8 qf1 = __builtin_bit_cast(bf16x8, pack8(qtmp));
    f32x4 acc[4];
#pragma unroll
    for (int dc = 0; dc < 4; ++dc) acc[dc] = (f32x4){0.f, 0.f, 0.f, 0.f};
    float m_run = -1e30f, l_run = 0.f;
    const int ig = qbase + c;
    const int srow = tid >> 3, sdb = tid & 7;
    const int vcol = (((srow >> 3) ^ (sdb & 3)) << 3) | (srow & 7);
    const float LOG2E = 1.4426950408889634f;
    for (int jt = 0; jt <= jt_last; ++jt) {
        __syncthreads();
        {
            const size_t g = head_off + (size_t)(jt * 32 + srow) * DH + sdb * 8;
            float kbuf[8];
            *(float4*)&kbuf[0] = *(const float4*)(k + g);
            *(float4*)&kbuf[4] = *(const float4*)(k + g + 4);
            *(uint4*)&kts[srow * KT_STRIDE + sdb * 8] = pack8(kbuf);
            float vbuf[8];
            *(float4*)&vbuf[0] = *(const float4*)(v + g);
            *(float4*)&vbuf[4] = *(const float4*)(v + g + 4);
#pragma unroll
            for (int i = 0; i < 8; ++i)
                vts[(sdb * 8 + i) * VT_STRIDE + vcol] = f2bf(vbuf[i]);
        }
        __syncthreads();
        if (jt > my_diag) continue;
        f32x4 st[2];
#pragma unroll
        for (int mt = 0; mt < 2; ++mt) {
            const unsigned short* krow = &kts[(mt * 16 + c) * KT_STRIDE + quad * 8];
            bf16x8 ka0 = __builtin_bit_cast(bf16x8, *(const uint4*)krow);
            bf16x8 ka1 = __builtin_bit_cast(bf16x8, *(const uint4*)(krow + 32));
            f32x4 a = (f32x4){0.f, 0.f, 0.f, 0.f};
            a = MFMA16(ka0, qf0, a);
            a = MFMA16(ka1, qf1, a);
            st[mt] = a;
        }
        float tv[8];
#pragma unroll
        for (int mt = 0; mt < 2; ++mt)
#pragma unroll
            for (int r = 0; r < 4; ++r) {
                const int jg = jt * 32 + mt * 16 + quad * 4 + r;
                const float s = st[mt][r] * 0.125f;
                tv[mt * 4 + r] = (jg > ig) ? -1e30f : s;
            }
        float tm = tv[0];
#pragma unroll
        for (int i = 1; i < 8; ++i) tm = fmaxf(tm, tv[i]);
        tm = fmaxf(tm, __shfl_xor(tm, 16, 64));
        tm = fmaxf(tm, __shfl_xor(tm, 32, 64));
        const float m_new = fmaxf(m_run, tm);
        const float mb = m_new * LOG2E;
        float p[8], ps = 0.f;
#pragma unroll
        for (int i = 0; i < 8; ++i) {
            p[i] = __builtin_amdgcn_exp2f(tv[i] * LOG2E - mb);
            ps += p[i];
        }
        ps += __shfl_xor(ps, 16, 64);
        ps += __shfl_xor(ps, 32, 64);
        const float alpha = __builtin_amdgcn_exp2f((m_run - m_new) * LOG2E);
        l_run = l_run * alpha + ps;
        m_run = m_new;
        unsigned short* pwf = pts[wave];
#pragma unroll
        for (int mt = 0; mt < 2; ++mt)
#pragma unroll
            for (int r = 0; r < 4; ++r)
                pwf[c * 40 + mt * 16 + quad * 4 + r] = f2bf(p[mt * 4 + r]);
        float ar[4];
#pragma unroll
        for (int r = 0; r < 4; ++r)
            ar[r] = __shfl(alpha, (quad << 4) + quad * 4 + r, 64);
#pragma unroll
        for (int dc = 0; dc < 4; ++dc)
#pragma unroll
            for (int r = 0; r < 4; ++r) acc[dc][r] *= ar[r];
        bf16x8 pf = __builtin_bit_cast(bf16x8, *(const uint4*)&pwf[c * 40 + quad * 8]);
#pragma unroll
        for (int dc = 0; dc < 4; ++dc) {
            const int vrow = dc * 16 + c;
            const int blk = quad ^ ((vrow >> 3) & 3);
            const unsigned short* vp = &vts[vrow * VT_STRIDE + blk * 8];
            uint2 a0 = *(const uint2*)vp;
            uint2 a1 = *(const uint2*)(vp + 4);
            uint4 u; u.x = a0.x; u.y = a0.y; u.z = a1.x; u.w = a1.y;
            bf16x8 vf = __builtin_bit_cast(bf16x8, u);
            acc[dc] = MFMA16(pf, vf, acc[dc]);
        }
    }
    float linv[4];
#pragma unroll
    for (int r = 0; r < 4; ++r) {
        const float lr = __shfl(l_run, (quad << 4) + quad * 4 + r, 64);
        linv[r] = 1.0f / lr;
    }
    float* ob = out + head_off;
#pragma unroll
    for (int dc = 0; dc < 4; ++dc)
#pragma unroll
        for (int r = 0; r < 4; ++r) {
            const size_t idx = (size_t)(qbase + quad * 4 + r) * DH + dc * 16 + c;
            ob[idx] = acc[dc][r] * linv[r];
        }
}

extern "C" void kernel_launch(void* const* d_in, const int* in_sizes, int n_in,
                              void* d_out, int out_size, void* d_ws, size_t ws_size,
                              hipStream_t stream) {
    const float* q = (const float*)d_in[0];
    const float* k = (const float*)d_in[1];
    const float* v = (const float*)d_in[2];
    float* o = (float*)d_out;
    const size_t img_bytes = (size_t)2 * 64 * 64 * 4096;  // K + V images
    if (ws_size >= img_bytes) {
        uint4* kimg = (uint4*)d_ws;
        uint4* vimg = kimg + (size_t)64 * 64 * 256;
        void* args[] = {(void*)&q, (void*)&k, (void*)&v,
                        (void*)&kimg, (void*)&vimg, (void*)&o};
        hipError_t e = hipLaunchCooperativeKernel(
            (const void*)fa_fused, dim3(1024), dim3(256), args, 0, stream);
        if (e != hipSuccess) {
            (void)hipGetLastError();  // clear sticky error, use 2-kernel path
            hipLaunchKernelGGL(prep_kv, dim3(8192), dim3(256), 0, stream,
                               k, v, kimg, vimg);
            hipLaunchKernelGGL(fa_kernel, dim3(1024), dim3(256), 0, stream,
                               q, kimg, vimg, o);
        }
    } else {
        hipLaunchKernelGGL(fa_kernel_fb, dim3(2048), dim3(256), 0, stream, q, k, v, o);
    }
}

// Round 7
// 300.032 us; speedup vs baseline: 1.6317x; 1.3694x over previous
//
#include <hip/hip_runtime.h>

#define S_LEN 2048
#define DH 64

typedef float f32x4 __attribute__((ext_vector_type(4)));
typedef __bf16 bf16x8 __attribute__((ext_vector_type(8)));
typedef unsigned u32x2v __attribute__((ext_vector_type(2)));

#define MFMA16(A, B, C) __builtin_amdgcn_mfma_f32_16x16x32_bf16(A, B, C, 0, 0, 0)

#ifdef __has_builtin
#if __has_builtin(__builtin_amdgcn_permlane16_swap) && __has_builtin(__builtin_amdgcn_permlane32_swap)
#define HAVE_PLSWAP 1
#endif
#if __has_builtin(__builtin_amdgcn_s_setprio)
#define SETPRIO(x) __builtin_amdgcn_s_setprio(x)
#endif
#endif
#ifndef HAVE_PLSWAP
#define HAVE_PLSWAP 0
#endif
#ifndef SETPRIO
#define SETPRIO(x)
#endif

__device__ __forceinline__ unsigned short f2bf(float f) {
    unsigned u = __builtin_bit_cast(unsigned, f);
    u += 0x7fffu + ((u >> 16) & 1u);
    return (unsigned short)(u >> 16);
}

__device__ __forceinline__ uint4 pack8(const float* s) {
    unsigned short h[8];
#pragma unroll
    for (int i = 0; i < 8; ++i) h[i] = f2bf(s[i]);
    return *(const uint4*)h;
}

// truncating pack (1 VALU op); bias cancels in O = (P V)/(P 1)
__device__ __forceinline__ unsigned pack_tr(float a, float b) {
    return __builtin_amdgcn_perm(__builtin_bit_cast(unsigned, b),
                                 __builtin_bit_cast(unsigned, a), 0x07060302u);
}

__device__ __forceinline__ bf16x8 ld128(const unsigned short* p) {
    return __builtin_bit_cast(bf16x8, *(const uint4*)p);
}

__device__ __forceinline__ bf16x8 ones8() {
    uint4 ou; ou.x = 0x3F803F80u; ou.y = ou.x; ou.z = ou.x; ou.w = ou.x;
    return __builtin_bit_cast(bf16x8, ou);
}

// ---- cross-lane P redistribution: C-layout (4 keys/lane) -> A-frag --------
__device__ __forceinline__ void pl32pair(unsigned& x, unsigned& y) {
#if HAVE_PLSWAP
    u32x2v r = __builtin_amdgcn_permlane32_swap(x, y, false, false);
    x = r[0]; y = r[1];
#else
    unsigned sx = __shfl_xor(x, 32, 64);
    unsigned sy = __shfl_xor(y, 32, 64);
    const bool hi = (threadIdx.x & 32) != 0;
    unsigned nx = hi ? sy : x;
    unsigned ny = hi ? y : sx;
    x = nx; y = ny;
#endif
}

__device__ __forceinline__ void pl16pair(unsigned& x, unsigned& y) {
#if HAVE_PLSWAP
    u32x2v r = __builtin_amdgcn_permlane16_swap(x, y, false, false);
    x = r[0]; y = r[1];
#else
    unsigned sx = __shfl_xor(x, 16, 64);
    unsigned sy = __shfl_xor(y, 16, 64);
    const bool odd = (threadIdx.x & 16) != 0;
    unsigned nx = odd ? sy : x;
    unsigned ny = odd ? y : sx;
    x = nx; y = ny;
#endif
}

// Inputs (lane quad q, col c): A0 = keys {4q,4q+1} of mt=2h, B0 = {4q+2,4q+3},
// A1/B1 same for mt=2h+1. Output: A-frag, lane q' holding keys q'*8..q'*8+7
// (relative to the 32-key half) of row c.
__device__ __forceinline__ bf16x8 frag_from(unsigned A0, unsigned B0,
                                            unsigned A1, unsigned B1) {
    pl32pair(A0, A1);
    pl16pair(A0, A1);   // A0=w0  A1=w2
    pl32pair(B0, B1);
    pl16pair(B0, B1);   // B0=w1  B1=w3
    uint4 u; u.x = A0; u.y = B0; u.z = A1; u.w = B1;
    return __builtin_bit_cast(bf16x8, u);
}

// LDS tile layouts (per 64-key tile jt of one head):
//   kt: [64 keys][8 dim-blocks of 8 bf16], stored block j of row r holds
//       source dim-block j ^ (r & 7)  (read: f0/f1 below).
//   vt: [2 key-halves][64 dims][4 key-blocks of 8 bf16], stored block j of
//       dim d holds source key-block j ^ ((d>>1)&3) ^ ((d>>3)&3).
//       (the (d>>3) term makes the transpose-scatter WRITE ~conflict-free;
//        read vsw matches it.)

// ---------------- dual-strip body (phase 1): frags shared ------------------
// Strip A = hi rows (unmasked here), strip B = lo rows (MB: diagonal mask).
template <bool MB>
__device__ __forceinline__ void body2(
    const unsigned short* __restrict__ kt_, const unsigned short* __restrict__ vt_,
    const bf16x8* qA, const bf16x8* qB,
    f32x4 (&accA)[4], f32x4 (&accB)[4], f32x4& aclA, f32x4& aclB,
    int igB, int kb, int quad, int c)
{
    const int sw = c & 7;
    const bf16x8 ones = ones8();
    const int f0 = (quad ^ sw) << 3;
    const int f1 = ((quad | 4) ^ sw) << 3;
    bf16x8 pfA[2], pfB[2];
#pragma unroll
    for (int h = 0; h < 2; ++h) {
        unsigned pA[2][2], pB[2][2];
#pragma unroll
        for (int m = 0; m < 2; ++m) {
            const int mt = 2 * h + m;
            const unsigned short* kr = kt_ + (mt * 16 + c) * 64;
            bf16x8 k0 = ld128(kr + f0), k1 = ld128(kr + f1);
            {
                f32x4 s = (f32x4){0.f, 0.f, 0.f, 0.f};
                s = MFMA16(k0, qA[0], s);
                s = MFMA16(k1, qA[1], s);
                float p[4];
#pragma unroll
                for (int r = 0; r < 4; ++r) p[r] = __builtin_amdgcn_exp2f(s[r]);
                pA[m][0] = pack_tr(p[0], p[1]);
                pA[m][1] = pack_tr(p[2], p[3]);
            }
            {
                f32x4 s = (f32x4){0.f, 0.f, 0.f, 0.f};
                s = MFMA16(k0, qB[0], s);
                s = MFMA16(k1, qB[1], s);
                float p[4];
#pragma unroll
                for (int r = 0; r < 4; ++r) {
                    float e = __builtin_amdgcn_exp2f(s[r]);
                    if (MB) {
                        const int jg = kb + mt * 16 + quad * 4 + r;
                        e = (jg > igB) ? 0.f : e;
                    }
                    p[r] = e;
                }
                pB[m][0] = pack_tr(p[0], p[1]);
                pB[m][1] = pack_tr(p[2], p[3]);
            }
        }
        pfA[h] = frag_from(pA[0][0], pA[0][1], pA[1][0], pA[1][1]);
        aclA = MFMA16(pfA[h], ones, aclA);
        pfB[h] = frag_from(pB[0][0], pB[0][1], pB[1][0], pB[1][1]);
        aclB = MFMA16(pfB[h], ones, aclB);
    }
#pragma unroll
    for (int dc = 0; dc < 4; ++dc) {
        const int d = dc * 16 + c;
        const int vsw = ((d >> 1) & 3) ^ ((d >> 3) & 3);
        const int vo = d * 32 + ((quad ^ vsw) << 3);
        bf16x8 v0 = ld128(vt_ + vo), v1 = ld128(vt_ + vo + 2048);
        accA[dc] = MFMA16(pfA[0], v0, accA[dc]);
        accA[dc] = MFMA16(pfA[1], v1, accA[dc]);
        accB[dc] = MFMA16(pfB[0], v0, accB[dc]);
        accB[dc] = MFMA16(pfB[1], v1, accB[dc]);
    }
}

// ---------------- single-strip body (phase 2): one key-partial -------------
template <bool MASK>
__device__ __forceinline__ void body1(
    const unsigned short* __restrict__ kt_, const unsigned short* __restrict__ vt_,
    const bf16x8* qA, f32x4 (&acc)[4], f32x4& acl,
    int ig, int kb, int quad, int c)
{
    const int sw = c & 7;
    const bf16x8 ones = ones8();
    const int f0 = (quad ^ sw) << 3;
    const int f1 = ((quad | 4) ^ sw) << 3;
    bf16x8 pf[2];
#pragma unroll
    for (int h = 0; h < 2; ++h) {
        unsigned pA[2][2];
#pragma unroll
        for (int m = 0; m < 2; ++m) {
            const int mt = 2 * h + m;
            const unsigned short* kr = kt_ + (mt * 16 + c) * 64;
            bf16x8 k0 = ld128(kr + f0), k1 = ld128(kr + f1);
            f32x4 s = (f32x4){0.f, 0.f, 0.f, 0.f};
            s = MFMA16(k0, qA[0], s);
            s = MFMA16(k1, qA[1], s);
            float p[4];
#pragma unroll
            for (int r = 0; r < 4; ++r) {
                float e = __builtin_amdgcn_exp2f(s[r]);
                if (MASK) {
                    const int jg = kb + mt * 16 + quad * 4 + r;
                    e = (jg > ig) ? 0.f : e;
                }
                p[r] = e;
            }
            pA[m][0] = pack_tr(p[0], p[1]);
            pA[m][1] = pack_tr(p[2], p[3]);
        }
        pf[h] = frag_from(pA[0][0], pA[0][1], pA[1][0], pA[1][1]);
        acl = MFMA16(pf[h], ones, acl);
    }
#pragma unroll
    for (int dc = 0; dc < 4; ++dc) {
        const int d = dc * 16 + c;
        const int vsw = ((d >> 1) & 3) ^ ((d >> 3) & 3);
        const int vo = d * 32 + ((quad ^ vsw) << 3);
        bf16x8 v0 = ld128(vt_ + vo), v1 = ld128(vt_ + vo + 2048);
        acc[dc] = MFMA16(pf[0], v0, acc[dc]);
        acc[dc] = MFMA16(pf[1], v1, acc[dc]);
    }
}

__device__ __forceinline__ void write_strip(float* __restrict__ ob,
                                            const f32x4* acc, const f32x4 acl,
                                            int rowbase, int quad, int c) {
    float linv[4];
#pragma unroll
    for (int r = 0; r < 4; ++r) linv[r] = 1.0f / acl[r];
#pragma unroll
    for (int dc = 0; dc < 4; ++dc)
#pragma unroll
        for (int r = 0; r < 4; ++r) {
            const size_t idx =
                (size_t)(rowbase + quad * 4 + r) * DH + dc * 16 + c;
            ob[idx] = acc[dc][r] * linv[r];
        }
}

// ---------------- single self-sufficient kernel ----------------------------
// Grid 1024 = 64 heads x 16 ci-blocks. Block ci owns 64-row chunk ci (lo) +
// chunk 31-ci (hi); each wave a 16-row strip of each. Round-3 schedule:
// jt = 0..ci dual strips (lo retires at its diagonal), jt = ci+1..31-ci one
// hi-strip key-partial per tile alternating accA/accB, in-register merge.
// Staging is now self-contained: fp32 K/V -> regs (issued one full body
// ahead) -> bf16 convert -> swizzled LDS tiles. No prep kernel, no images,
// no cross-block sync (rounds 5/6 proved ANY grid-wide sync costs ~200µs+).
// Still exactly one __syncthreads per tile.
__global__ __launch_bounds__(256, 4) void fa_kernel(
    const float* __restrict__ q,
    const float* __restrict__ kg,
    const float* __restrict__ vg,
    float* __restrict__ out)
{
    __shared__ unsigned short kt[2][64 * 64];     // 2 x 8 KB
    __shared__ unsigned short vt[2][2 * 64 * 32]; // 2 x 8 KB

    const int tid  = threadIdx.x;
    const int lane = tid & 63;
    const int wave = tid >> 6;
    const int quad = lane >> 4;
    const int c    = lane & 15;

    const int bid = blockIdx.x;
    const int bh  = bid & 63;
    const int ci  = bid >> 6;                     // 0..15
    const int last = 31 - ci;
    const int hib = last * 64 + wave * 16;        // hi strip base row
    const int lob = ci * 64 + wave * 16;          // lo strip base row

    const size_t head_off = (size_t)bh * S_LEN * DH;

    // staging thread mapping: rows (sr, sr+32) x dim-block sb
    const int sr = tid >> 3;                      // 0..31
    const int sb = tid & 7;                       // 0..7
    const float* kbase = kg + head_off + sb * 8;
    const float* vbase = vg + head_off + sb * 8;

    float kr0[8], kr1[8], vr0[8], vr1[8];         // fp32 tile in flight

    auto LOAD = [&](int jt) {                     // issue global loads, tile jt
        const size_t o0 = (size_t)(jt * 64 + sr) * 64;
        const size_t o1 = o0 + 32 * 64;
        *(float4*)&kr0[0] = *(const float4*)(kbase + o0);
        *(float4*)&kr0[4] = *(const float4*)(kbase + o0 + 4);
        *(float4*)&kr1[0] = *(const float4*)(kbase + o1);
        *(float4*)&kr1[4] = *(const float4*)(kbase + o1 + 4);
        *(float4*)&vr0[0] = *(const float4*)(vbase + o0);
        *(float4*)&vr0[4] = *(const float4*)(vbase + o0 + 4);
        *(float4*)&vr1[0] = *(const float4*)(vbase + o1);
        *(float4*)&vr1[4] = *(const float4*)(vbase + o1 + 4);
    };

    auto WRITE = [&](int b) {                     // regs -> bf16 LDS tile b
        const int kcol = (sb ^ (sr & 7)) << 3;    // row-permuted: conflict-free
        *(uint4*)&kt[b][sr * 64 + kcol]        = pack8(kr0);
        *(uint4*)&kt[b][(sr + 32) * 64 + kcol] = pack8(kr1);
        const int kb4 = sr >> 3;                  // key-block within half
        const int k7  = sr & 7;
#pragma unroll
        for (int i = 0; i < 8; ++i) {
            const int d = sb * 8 + i;
            const int j = kb4 ^ ((d >> 1) & 3) ^ ((d >> 3) & 3);
            unsigned short* p = &vt[b][d * 32 + j * 8 + k7];
            p[0]    = f2bf(vr0[i]);               // key sr   (half 0)
            p[2048] = f2bf(vr1[i]);               // key sr+32 (half 1)
        }
    };

    LOAD(0);

    // Q fragments: [0,1] = hi strip, [2,3] = lo strip (log2-domain pre-scale)
    // -- independent work that hides the first tile's load latency
    const float SCALE = 0.125f * 1.4426950408889634f;
    bf16x8 qf[4];
#pragma unroll
    for (int s = 0; s < 2; ++s) {
        const int base = s ? lob : hib;
        const float* qrow = q + head_off + (size_t)(base + c) * DH;
        float t0[8], t1[8];
#pragma unroll
        for (int i = 0; i < 8; ++i) t0[i] = qrow[quad * 8 + i] * SCALE;
#pragma unroll
        for (int i = 0; i < 8; ++i) t1[i] = qrow[32 + quad * 8 + i] * SCALE;
        qf[s * 2 + 0] = __builtin_bit_cast(bf16x8, pack8(t0));
        qf[s * 2 + 1] = __builtin_bit_cast(bf16x8, pack8(t1));
    }

    WRITE(0);                                     // tile 0 -> buf 0
    LOAD(1 <= last ? 1 : 0);                      // prefetch tile 1

    f32x4 accA[4], accB[4];
#pragma unroll
    for (int dc = 0; dc < 4; ++dc) {
        accA[dc] = (f32x4){0.f, 0.f, 0.f, 0.f};
        accB[dc] = (f32x4){0.f, 0.f, 0.f, 0.f};
    }
    f32x4 aclA = (f32x4){0.f, 0.f, 0.f, 0.f};
    f32x4 aclB = (f32x4){0.f, 0.f, 0.f, 0.f};

    const int igA = hib + c;
    const int igB = lob + c;

    // ---- phase 1: jt = 0..ci, dual strips, shared frags ----
    int jt = 0;
    for (; jt <= ci; ++jt) {
        __syncthreads();   // tile jt visible; buf (jt+1)&1 free (body jt-1 done)
        if (jt < last) {
            WRITE((jt + 1) & 1);                  // regs hold tile jt+1
            LOAD(jt + 2 <= last ? jt + 2 : last); // issue tile jt+2
        }
        const unsigned short* K = kt[jt & 1];
        const unsigned short* V = vt[jt & 1];
        SETPRIO(1);
        if (jt < ci)
            body2<false>(K, V, qf, qf + 2, accA, accB, aclA, aclB,
                         igB, jt * 64, quad, c);
        else
            body2<true>(K, V, qf, qf + 2, accA, accB, aclA, aclB,
                        igB, jt * 64, quad, c);
        SETPRIO(0);
    }

    // ---- retire lo strip; accB becomes the hi strip's second key-partial
    write_strip(out + head_off, accB, aclB, lob, quad, c);
#pragma unroll
    for (int dc = 0; dc < 4; ++dc) accB[dc] = (f32x4){0.f, 0.f, 0.f, 0.f};
    aclB = (f32x4){0.f, 0.f, 0.f, 0.f};

    // ---- phase 2: jt = ci+1..last, single strip, alternating partials ----
    for (; jt <= last; ++jt) {
        __syncthreads();
        if (jt < last) {
            WRITE((jt + 1) & 1);
            LOAD(jt + 2 <= last ? jt + 2 : last);
        }
        const unsigned short* K = kt[jt & 1];
        const unsigned short* V = vt[jt & 1];
        const int kb = jt * 64;
        SETPRIO(1);
        if ((jt ^ ci) & 1) {
            if (jt == last) body1<true >(K, V, qf, accB, aclB, igA, kb, quad, c);
            else            body1<false>(K, V, qf, accB, aclB, igA, kb, quad, c);
        } else {
            if (jt == last) body1<true >(K, V, qf, accA, aclA, igA, kb, quad, c);
            else            body1<false>(K, V, qf, accA, aclA, igA, kb, quad, c);
        }
        SETPRIO(0);
    }

    // ---- merge key-partials in-register, final epilogue for hi strip
#pragma unroll
    for (int dc = 0; dc < 4; ++dc) accA[dc] += accB[dc];
    aclA += aclB;
    write_strip(out + head_off, accA, aclA, hib, quad, c);
}

extern "C" void kernel_launch(void* const* d_in, const int* in_sizes, int n_in,
                              void* d_out, int out_size, void* d_ws, size_t ws_size,
                              hipStream_t stream) {
    const float* q = (const float*)d_in[0];
    const float* k = (const float*)d_in[1];
    const float* v = (const float*)d_in[2];
    float* o = (float*)d_out;
    hipLaunchKernelGGL(fa_kernel, dim3(1024), dim3(256), 0, stream, q, k, v, o);
}

// Round 8
// 191.542 us; speedup vs baseline: 2.5560x; 1.5664x over previous
//
#include <hip/hip_runtime.h>

#define S_LEN 2048
#define DH 64

typedef float f32x4 __attribute__((ext_vector_type(4)));
typedef __bf16 bf16x8 __attribute__((ext_vector_type(8)));
typedef unsigned u32x2v __attribute__((ext_vector_type(2)));

#define MFMA16(A, B, C) __builtin_amdgcn_mfma_f32_16x16x32_bf16(A, B, C, 0, 0, 0)

#ifdef __has_builtin
#if __has_builtin(__builtin_amdgcn_permlane16_swap) && __has_builtin(__builtin_amdgcn_permlane32_swap)
#define HAVE_PLSWAP 1
#endif
#if __has_builtin(__builtin_amdgcn_global_load_lds)
#define HAVE_GLDS 1
#endif
#if __has_builtin(__builtin_amdgcn_s_setprio)
#define SETPRIO(x) __builtin_amdgcn_s_setprio(x)
#endif
#endif
#ifndef HAVE_PLSWAP
#define HAVE_PLSWAP 0
#endif
#ifndef HAVE_GLDS
#define HAVE_GLDS 0
#endif
#ifndef SETPRIO
#define SETPRIO(x)
#endif

__device__ __forceinline__ unsigned short f2bf(float f) {
    unsigned u = __builtin_bit_cast(unsigned, f);
    u += 0x7fffu + ((u >> 16) & 1u);
    return (unsigned short)(u >> 16);
}

__device__ __forceinline__ uint4 pack8(const float* s) {
    unsigned short h[8];
#pragma unroll
    for (int i = 0; i < 8; ++i) h[i] = f2bf(s[i]);
    return *(const uint4*)h;
}

// truncating pack (1 VALU op); bias cancels in O = (P V)/(P 1)
__device__ __forceinline__ unsigned pack_tr(float a, float b) {
    return __builtin_amdgcn_perm(__builtin_bit_cast(unsigned, b),
                                 __builtin_bit_cast(unsigned, a), 0x07060302u);
}

__device__ __forceinline__ bf16x8 ld128(const unsigned short* p) {
    return __builtin_bit_cast(bf16x8, *(const uint4*)p);
}

__device__ __forceinline__ bf16x8 ones8() {
    uint4 ou; ou.x = 0x3F803F80u; ou.y = ou.x; ou.z = ou.x; ou.w = ou.x;
    return __builtin_bit_cast(bf16x8, ou);
}

// ---- cross-lane P redistribution: C-layout (4 keys/lane) -> A-frag --------
__device__ __forceinline__ void pl32pair(unsigned& x, unsigned& y) {
#if HAVE_PLSWAP
    u32x2v r = __builtin_amdgcn_permlane32_swap(x, y, false, false);
    x = r[0]; y = r[1];
#else
    unsigned sx = __shfl_xor(x, 32, 64);
    unsigned sy = __shfl_xor(y, 32, 64);
    const bool hi = (threadIdx.x & 32) != 0;
    unsigned nx = hi ? sy : x;
    unsigned ny = hi ? y : sx;
    x = nx; y = ny;
#endif
}

__device__ __forceinline__ void pl16pair(unsigned& x, unsigned& y) {
#if HAVE_PLSWAP
    u32x2v r = __builtin_amdgcn_permlane16_swap(x, y, false, false);
    x = r[0]; y = r[1];
#else
    unsigned sx = __shfl_xor(x, 16, 64);
    unsigned sy = __shfl_xor(y, 16, 64);
    const bool odd = (threadIdx.x & 16) != 0;
    unsigned nx = odd ? sy : x;
    unsigned ny = odd ? y : sx;
    x = nx; y = ny;
#endif
}

// Inputs (lane quad q, col c): A0 = keys {4q,4q+1} of mt=2h, B0 = {4q+2,4q+3},
// A1/B1 same for mt=2h+1. Output: A-frag, lane q' holding keys q'*8..q'*8+7
// (relative to the 32-key half) of row c.
__device__ __forceinline__ bf16x8 frag_from(unsigned A0, unsigned B0,
                                            unsigned A1, unsigned B1) {
    pl32pair(A0, A1);
    pl16pair(A0, A1);   // A0=w0  A1=w2
    pl32pair(B0, B1);
    pl16pair(B0, B1);   // B0=w1  B1=w3
    uint4 u; u.x = A0; u.y = B0; u.z = A1; u.w = B1;
    return __builtin_bit_cast(bf16x8, u);
}

// ---- async global->LDS (16B/lane, linear dest = our exact layout) ---------
__device__ __forceinline__ void glds16(const uint4* g, unsigned short* l) {
#if HAVE_GLDS
    __builtin_amdgcn_global_load_lds(
        (const __attribute__((address_space(1))) uint4*)g,
        (__attribute__((address_space(3))) uint4*)l, 16, 0, 0);
#else
    *(uint4*)l = *g;
#endif
}

// ---------------- fused pre-pass: K and V -> swizzled bf16 tile images -----
// V-path LDS transpose uses an XOR row-group swizzle (write conflicts
// 16-way -> 4-way); reads invert it, so the emitted vimg bytes are identical
// to the unswizzled version (verified round 4).
__global__ __launch_bounds__(256) void prep_kv(const float* __restrict__ k,
                                               const float* __restrict__ v,
                                               uint4* __restrict__ kimg,
                                               uint4* __restrict__ vimg) {
    __shared__ unsigned short tr[64 * 40];
    const int bid = blockIdx.x;
    const int t = threadIdx.x;
    if (bid < 4096) {
        const int r = t >> 3, b = t & 7;
        const int srcblk = b ^ (r & 7);
        const float* src = k + ((size_t)bid * 32 + r) * 64 + srcblk * 8;
        float buf[8];
        *(float4*)&buf[0] = *(const float4*)src;
        *(float4*)&buf[4] = *(const float4*)(src + 4);
        kimg[(size_t)bid * 256 + t] = pack8(buf);
    } else {
        const int vb = bid - 4096;
        const int r = t >> 3, cb = t & 7;
        const float* src = v + ((size_t)vb * 32 + r) * 64 + cb * 8;
        float buf[8];
        *(float4*)&buf[0] = *(const float4*)src;
        *(float4*)&buf[4] = *(const float4*)(src + 4);
        const int rswz = (((r >> 3) ^ cb) & 3) * 8 + (r & 7);
#pragma unroll
        for (int i = 0; i < 8; ++i)
            tr[(cb * 8 + i) * 40 + rswz] = f2bf(buf[i]);
        __syncthreads();
        const int d = t >> 2, kb = t & 3;
        const int skb = kb ^ ((d >> 1) & 3);
        const int sloc = skb ^ ((d >> 3) & 3);
        vimg[(size_t)vb * 256 + t] = *(const uint4*)&tr[d * 40 + sloc * 8];
    }
}

// ---------------- dual-strip body (phase 1): frags shared ------------------
// Phase-batched for ILP (round-4 theory, now with a real 128-VGPR budget):
// all QK MFMAs -> all exp2+packs -> V loads -> permlane frags + l-MFMAs ->
// all PV MFMAs. Long producer->consumer distance per phase.
template <bool MB>
__device__ __forceinline__ void body2(
    const unsigned short* __restrict__ kt_, const unsigned short* __restrict__ vt_,
    const bf16x8* qA, const bf16x8* qB,
    f32x4 (&accA)[4], f32x4 (&accB)[4], f32x4& aclA, f32x4& aclB,
    int igB, int kb, int quad, int c)
{
    const int sw = c & 7;
    const bf16x8 ones = ones8();
    const int f0 = (quad ^ sw) << 3;
    const int f1 = ((quad | 4) ^ sw) << 3;

    // ---- QK: 8 independent 2-MFMA chains ----
    f32x4 sA[4], sB[4];
#pragma unroll
    for (int mt = 0; mt < 4; ++mt) {
        const unsigned short* kr = kt_ + (mt * 16 + c) * 64;
        bf16x8 k0 = ld128(kr + f0), k1 = ld128(kr + f1);
        f32x4 a = (f32x4){0.f, 0.f, 0.f, 0.f};
        a = MFMA16(k0, qA[0], a);
        a = MFMA16(k1, qA[1], a);
        sA[mt] = a;
        f32x4 b = (f32x4){0.f, 0.f, 0.f, 0.f};
        b = MFMA16(k0, qB[0], b);
        b = MFMA16(k1, qB[1], b);
        sB[mt] = b;
    }

    // ---- exp2 + pack (trans pipe streams; MFMA latency long hidden) ----
    unsigned pA[4][2], pB[4][2];
#pragma unroll
    for (int mt = 0; mt < 4; ++mt) {
        float a0 = __builtin_amdgcn_exp2f(sA[mt][0]);
        float a1 = __builtin_amdgcn_exp2f(sA[mt][1]);
        float a2 = __builtin_amdgcn_exp2f(sA[mt][2]);
        float a3 = __builtin_amdgcn_exp2f(sA[mt][3]);
        pA[mt][0] = pack_tr(a0, a1);
        pA[mt][1] = pack_tr(a2, a3);
        float b0 = __builtin_amdgcn_exp2f(sB[mt][0]);
        float b1 = __builtin_amdgcn_exp2f(sB[mt][1]);
        float b2 = __builtin_amdgcn_exp2f(sB[mt][2]);
        float b3 = __builtin_amdgcn_exp2f(sB[mt][3]);
        if (MB) {
            const int jg = kb + mt * 16 + quad * 4;
            b0 = (jg + 0 > igB) ? 0.f : b0;
            b1 = (jg + 1 > igB) ? 0.f : b1;
            b2 = (jg + 2 > igB) ? 0.f : b2;
            b3 = (jg + 3 > igB) ? 0.f : b3;
        }
        pB[mt][0] = pack_tr(b0, b1);
        pB[mt][1] = pack_tr(b2, b3);
    }

    // ---- V frag loads early (latency hides under permlanes/l-MFMAs) ----
    const int vsw = (c >> 1) & 3;
    bf16x8 vf[4][2];
#pragma unroll
    for (int dc = 0; dc < 4; ++dc) {
        const int vo = (dc * 16 + c) * 32 + ((quad ^ vsw) << 3);
        vf[dc][0] = ld128(vt_ + vo);
        vf[dc][1] = ld128(vt_ + vo + 2048);
    }

    // ---- cross-lane frags + l via ones-MFMA ----
    bf16x8 pfA[2], pfB[2];
    pfA[0] = frag_from(pA[0][0], pA[0][1], pA[1][0], pA[1][1]);
    pfA[1] = frag_from(pA[2][0], pA[2][1], pA[3][0], pA[3][1]);
    pfB[0] = frag_from(pB[0][0], pB[0][1], pB[1][0], pB[1][1]);
    pfB[1] = frag_from(pB[2][0], pB[2][1], pB[3][0], pB[3][1]);
    aclA = MFMA16(pfA[0], ones, aclA);
    aclA = MFMA16(pfA[1], ones, aclA);
    aclB = MFMA16(pfB[0], ones, aclB);
    aclB = MFMA16(pfB[1], ones, aclB);

    // ---- PV (4 independent acc chains per strip) ----
#pragma unroll
    for (int dc = 0; dc < 4; ++dc) {
        accA[dc] = MFMA16(pfA[0], vf[dc][0], accA[dc]);
        accA[dc] = MFMA16(pfA[1], vf[dc][1], accA[dc]);
        accB[dc] = MFMA16(pfB[0], vf[dc][0], accB[dc]);
        accB[dc] = MFMA16(pfB[1], vf[dc][1], accB[dc]);
    }
}

// ---------------- single-strip body (phase 2): one key-partial -------------
template <bool MASK>
__device__ __forceinline__ void body1(
    const unsigned short* __restrict__ kt_, const unsigned short* __restrict__ vt_,
    const bf16x8* qA, f32x4 (&acc)[4], f32x4& acl,
    int ig, int kb, int quad, int c)
{
    const int sw = c & 7;
    const bf16x8 ones = ones8();
    const int f0 = (quad ^ sw) << 3;
    const int f1 = ((quad | 4) ^ sw) << 3;

    f32x4 sA[4];
#pragma unroll
    for (int mt = 0; mt < 4; ++mt) {
        const unsigned short* kr = kt_ + (mt * 16 + c) * 64;
        bf16x8 k0 = ld128(kr + f0), k1 = ld128(kr + f1);
        f32x4 a = (f32x4){0.f, 0.f, 0.f, 0.f};
        a = MFMA16(k0, qA[0], a);
        a = MFMA16(k1, qA[1], a);
        sA[mt] = a;
    }

    unsigned pA[4][2];
#pragma unroll
    for (int mt = 0; mt < 4; ++mt) {
        float a0 = __builtin_amdgcn_exp2f(sA[mt][0]);
        float a1 = __builtin_amdgcn_exp2f(sA[mt][1]);
        float a2 = __builtin_amdgcn_exp2f(sA[mt][2]);
        float a3 = __builtin_amdgcn_exp2f(sA[mt][3]);
        if (MASK) {
            const int jg = kb + mt * 16 + quad * 4;
            a0 = (jg + 0 > ig) ? 0.f : a0;
            a1 = (jg + 1 > ig) ? 0.f : a1;
            a2 = (jg + 2 > ig) ? 0.f : a2;
            a3 = (jg + 3 > ig) ? 0.f : a3;
        }
        pA[mt][0] = pack_tr(a0, a1);
        pA[mt][1] = pack_tr(a2, a3);
    }

    const int vsw = (c >> 1) & 3;
    bf16x8 vf[4][2];
#pragma unroll
    for (int dc = 0; dc < 4; ++dc) {
        const int vo = (dc * 16 + c) * 32 + ((quad ^ vsw) << 3);
        vf[dc][0] = ld128(vt_ + vo);
        vf[dc][1] = ld128(vt_ + vo + 2048);
    }

    bf16x8 pf[2];
    pf[0] = frag_from(pA[0][0], pA[0][1], pA[1][0], pA[1][1]);
    pf[1] = frag_from(pA[2][0], pA[2][1], pA[3][0], pA[3][1]);
    acl = MFMA16(pf[0], ones, acl);
    acl = MFMA16(pf[1], ones, acl);

#pragma unroll
    for (int dc = 0; dc < 4; ++dc) {
        acc[dc] = MFMA16(pf[0], vf[dc][0], acc[dc]);
        acc[dc] = MFMA16(pf[1], vf[dc][1], acc[dc]);
    }
}

__device__ __forceinline__ void write_strip(float* __restrict__ ob,
                                            const f32x4* acc, const f32x4 acl,
                                            int rowbase, int quad, int c) {
    float linv[4];
#pragma unroll
    for (int r = 0; r < 4; ++r) linv[r] = 1.0f / acl[r];
#pragma unroll
    for (int dc = 0; dc < 4; ++dc)
#pragma unroll
        for (int r = 0; r < 4; ++r) {
            const size_t idx =
                (size_t)(rowbase + quad * 4 + r) * DH + dc * 16 + c;
            ob[idx] = acc[dc][r] * linv[r];
        }
}

// ---------------- main kernel: unified loop, 1 barrier/tile, prefetch ------
// Block ci (0..15) owns 64-row chunk ci (lo) + chunk 31-ci (hi). Each wave
// owns a 16-row strip of each. jt = 0..ci: both strips vs the staged tile
// (frags shared); lo strip masked+retired at jt==ci. jt = ci+1..31-ci: one
// key-partial of the hi strip per tile, alternating accA/accB by parity
// (static call sites); merged in-register at the end.
// amdgpu_waves_per_eu(4,4): grid = exactly 4 blocks/CU = 4 waves/EU, so pin
// the allocator's occupancy target there -> up to 128 VGPRs, no 64-reg
// self-cap, no spill (rounds 4/7 post-mortems: launch_bounds min alone left
// the allocator targeting 8 waves/EU it could never get).
__global__ __attribute__((amdgpu_flat_work_group_size(256, 256)))
__attribute__((amdgpu_waves_per_eu(4, 4))) void fa_kernel(
    const float* __restrict__ q,
    const uint4* __restrict__ kimg,
    const uint4* __restrict__ vimg,
    float* __restrict__ out)
{
    __shared__ unsigned short kt[2][64 * 64];     // 2 x 8 KB
    __shared__ unsigned short vt[2][2 * 64 * 32]; // 2 x 8 KB

    const int tid  = threadIdx.x;
    const int lane = tid & 63;
    const int wave = tid >> 6;
    const int quad = lane >> 4;
    const int c    = lane & 15;

    const int bid = blockIdx.x;
    const int bh  = bid & 63;
    const int ci  = bid >> 6;                     // 0..15
    const int last = 31 - ci;
    const int hib = last * 64 + wave * 16;        // hi strip base row
    const int lob = ci * 64 + wave * 16;          // lo strip base row

    const size_t head_off = (size_t)bh * S_LEN * DH;

    const uint4* kin = kimg + (size_t)bh * 16384;
    const uint4* vin = vimg + (size_t)bh * 16384;

    auto stage = [&](int jt, int b) {
        const uint4* kg = kin + jt * 512 + tid;
        const uint4* vg = vin + jt * 512 + tid;
        glds16(kg,       &kt[b][0] + (size_t)tid * 8);
        glds16(kg + 256, &kt[b][0] + (size_t)(tid + 256) * 8);
        glds16(vg,       &vt[b][0] + (size_t)tid * 8);
        glds16(vg + 256, &vt[b][0] + (size_t)(tid + 256) * 8);
    };

    stage(0, 0);  // issue first tile before Q prep; drained at first barrier

    // Q fragments: [0,1] = hi strip, [2,3] = lo strip (log2-domain pre-scale)
    const float SCALE = 0.125f * 1.4426950408889634f;
    bf16x8 qf[4];
#pragma unroll
    for (int s = 0; s < 2; ++s) {
        const int base = s ? lob : hib;
        const float* qrow = q + head_off + (size_t)(base + c) * DH;
        float t0[8], t1[8];
#pragma unroll
        for (int i = 0; i < 8; ++i) t0[i] = qrow[quad * 8 + i] * SCALE;
#pragma unroll
        for (int i = 0; i < 8; ++i) t1[i] = qrow[32 + quad * 8 + i] * SCALE;
        qf[s * 2 + 0] = __builtin_bit_cast(bf16x8, pack8(t0));
        qf[s * 2 + 1] = __builtin_bit_cast(bf16x8, pack8(t1));
    }

    f32x4 accA[4], accB[4];
#pragma unroll
    for (int dc = 0; dc < 4; ++dc) {
        accA[dc] = (f32x4){0.f, 0.f, 0.f, 0.f};
        accB[dc] = (f32x4){0.f, 0.f, 0.f, 0.f};
    }
    f32x4 aclA = (f32x4){0.f, 0.f, 0.f, 0.f};
    f32x4 aclB = (f32x4){0.f, 0.f, 0.f, 0.f};

    const int igA = hib + c;
    const int igB = lob + c;

    // ---- phase 1: jt = 0..ci, dual strips, shared frags ----
    int jt = 0;
    for (; jt <= ci; ++jt) {
        __syncthreads();                      // drains stage(jt)
        if (jt < last) stage(jt + 1, (jt + 1) & 1);
        const unsigned short* K = kt[jt & 1];
        const unsigned short* V = vt[jt & 1];
        SETPRIO(1);
        if (jt < ci)
            body2<false>(K, V, qf, qf + 2, accA, accB, aclA, aclB,
                         igB, jt * 64, quad, c);
        else
            body2<true>(K, V, qf, qf + 2, accA, accB, aclA, aclB,
                        igB, jt * 64, quad, c);
        SETPRIO(0);
    }

    // ---- retire lo strip; accB becomes the hi strip's second key-partial
    write_strip(out + head_off, accB, aclB, lob, quad, c);
#pragma unroll
    for (int dc = 0; dc < 4; ++dc) accB[dc] = (f32x4){0.f, 0.f, 0.f, 0.f};
    aclB = (f32x4){0.f, 0.f, 0.f, 0.f};

    // ---- phase 2: jt = ci+1..last, single strip, alternating partials ----
    for (; jt <= last; ++jt) {
        __syncthreads();                      // drains stage(jt)
        if (jt < last) stage(jt + 1, (jt + 1) & 1);
        const unsigned short* K = kt[jt & 1];
        const unsigned short* V = vt[jt & 1];
        const int kb = jt * 64;
        SETPRIO(1);
        if ((jt ^ ci) & 1) {
            if (jt == last) body1<true >(K, V, qf, accB, aclB, igA, kb, quad, c);
            else            body1<false>(K, V, qf, accB, aclB, igA, kb, quad, c);
        } else {
            if (jt == last) body1<true >(K, V, qf, accA, aclA, igA, kb, quad, c);
            else            body1<false>(K, V, qf, accA, aclA, igA, kb, quad, c);
        }
        SETPRIO(0);
    }

    // ---- merge key-partials in-register, final epilogue for hi strip
#pragma unroll
    for (int dc = 0; dc < 4; ++dc) accA[dc] += accB[dc];
    aclA += aclB;
    write_strip(out + head_off, accA, aclA, hib, quad, c);
}

// ---------------- fallback (self-contained, used if ws too small) ----------
#define KT_STRIDE 88
#define VT_STRIDE 36
__global__ __launch_bounds__(256) void fa_kernel_fb(
    const float* __restrict__ q, const float* __restrict__ k,
    const float* __restrict__ v, float* __restrict__ out)
{
    __shared__ unsigned short kts[32 * KT_STRIDE];
    __shared__ unsigned short vts[64 * VT_STRIDE];
    __shared__ unsigned short pts[4][16 * 40];
    const int tid = threadIdx.x, lane = tid & 63, wave = tid >> 6;
    const int quad = lane >> 4, c = lane & 15;
    const int bid = blockIdx.x, bh = bid & 63, qblk = 31 - (bid >> 6);
    const int qtile = qblk * 4 + wave, qbase = qtile * 16;
    const int my_diag = qtile >> 1, jt_last = (qblk * 4 + 3) >> 1;
    const size_t head_off = (size_t)bh * S_LEN * DH;
    const float* qrow = q + head_off + (size_t)(qbase + c) * DH;
    float qtmp[8];
#pragma unroll
    for (int i = 0; i < 8; ++i) qtmp[i] = qrow[quad * 8 + i];
    bf16x8 qf0 = __builtin_bit_cast(bf16x8, pack8(qtmp));
#pragma unroll
    for (int i = 0; i < 8; ++i) qtmp[i] = qrow[32 + quad * 8 + i];
    bf16x8 qf1 = __builtin_bit_cast(bf16x8, pack8(qtmp));
    f32x4 acc[4];
#pragma unroll
    for (int dc = 0; dc < 4; ++dc) acc[dc] = (f32x4){0.f, 0.f, 0.f, 0.f};
    float m_run = -1e30f, l_run = 0.f;
    const int ig = qbase + c;
    const int srow = tid >> 3, sdb = tid & 7;
    const int vcol = (((srow >> 3) ^ (sdb & 3)) << 3) | (srow & 7);
    const float LOG2E = 1.4426950408889634f;
    for (int jt = 0; jt <= jt_last; ++jt) {
        __syncthreads();
        {
            const size_t g = head_off + (size_t)(jt * 32 + srow) * DH + sdb * 8;
            float kbuf[8];
            *(float4*)&kbuf[0] = *(const float4*)(k + g);
            *(float4*)&kbuf[4] = *(const float4*)(k + g + 4);
            *(uint4*)&kts[srow * KT_STRIDE + sdb * 8] = pack8(kbuf);
            float vbuf[8];
            *(float4*)&vbuf[0] = *(const float4*)(v + g);
            *(float4*)&vbuf[4] = *(const float4*)(v + g + 4);
#pragma unroll
            for (int i = 0; i < 8; ++i)
                vts[(sdb * 8 + i) * VT_STRIDE + vcol] = f2bf(vbuf[i]);
        }
        __syncthreads();
        if (jt > my_diag) continue;
        f32x4 st[2];
#pragma unroll
        for (int mt = 0; mt < 2; ++mt) {
            const unsigned short* krow = &kts[(mt * 16 + c) * KT_STRIDE + quad * 8];
            bf16x8 ka0 = __builtin_bit_cast(bf16x8, *(const uint4*)krow);
            bf16x8 ka1 = __builtin_bit_cast(bf16x8, *(const uint4*)(krow + 32));
            f32x4 a = (f32x4){0.f, 0.f, 0.f, 0.f};
            a = MFMA16(ka0, qf0, a);
            a = MFMA16(ka1, qf1, a);
            st[mt] = a;
        }
        float tv[8];
#pragma unroll
        for (int mt = 0; mt < 2; ++mt)
#pragma unroll
            for (int r = 0; r < 4; ++r) {
                const int jg = jt * 32 + mt * 16 + quad * 4 + r;
                const float s = st[mt][r] * 0.125f;
                tv[mt * 4 + r] = (jg > ig) ? -1e30f : s;
            }
        float tm = tv[0];
#pragma unroll
        for (int i = 1; i < 8; ++i) tm = fmaxf(tm, tv[i]);
        tm = fmaxf(tm, __shfl_xor(tm, 16, 64));
        tm = fmaxf(tm, __shfl_xor(tm, 32, 64));
        const float m_new = fmaxf(m_run, tm);
        const float mb = m_new * LOG2E;
        float p[8], ps = 0.f;
#pragma unroll
        for (int i = 0; i < 8; ++i) {
            p[i] = __builtin_amdgcn_exp2f(tv[i] * LOG2E - mb);
            ps += p[i];
        }
        ps += __shfl_xor(ps, 16, 64);
        ps += __shfl_xor(ps, 32, 64);
        const float alpha = __builtin_amdgcn_exp2f((m_run - m_new) * LOG2E);
        l_run = l_run * alpha + ps;
        m_run = m_new;
        unsigned short* pwf = pts[wave];
#pragma unroll
        for (int mt = 0; mt < 2; ++mt)
#pragma unroll
            for (int r = 0; r < 4; ++r)
                pwf[c * 40 + mt * 16 + quad * 4 + r] = f2bf(p[mt * 4 + r]);
        float ar[4];
#pragma unroll
        for (int r = 0; r < 4; ++r)
            ar[r] = __shfl(alpha, (quad << 4) + quad * 4 + r, 64);
#pragma unroll
        for (int dc = 0; dc < 4; ++dc)
#pragma unroll
            for (int r = 0; r < 4; ++r) acc[dc][r] *= ar[r];
        bf16x8 pf = __builtin_bit_cast(bf16x8, *(const uint4*)&pwf[c * 40 + quad * 8]);
#pragma unroll
        for (int dc = 0; dc < 4; ++dc) {
            const int vrow = dc * 16 + c;
            const int blk = quad ^ ((vrow >> 3) & 3);
            const unsigned short* vp = &vts[vrow * VT_STRIDE + blk * 8];
            uint2 a0 = *(const uint2*)vp;
            uint2 a1 = *(const uint2*)(vp + 4);
            uint4 u; u.x = a0.x; u.y = a0.y; u.z = a1.x; u.w = a1.y;
            bf16x8 vf = __builtin_bit_cast(bf16x8, u);
            acc[dc] = MFMA16(pf, vf, acc[dc]);
        }
    }
    float linv[4];
#pragma unroll
    for (int r = 0; r < 4; ++r) {
        const float lr = __shfl(l_run, (quad << 4) + quad * 4 + r, 64);
        linv[r] = 1.0f / lr;
    }
    float* ob = out + head_off;
#pragma unroll
    for (int dc = 0; dc < 4; ++dc)
#pragma unroll
        for (int r = 0; r < 4; ++r) {
            const size_t idx = (size_t)(qbase + quad * 4 + r) * DH + dc * 16 + c;
            ob[idx] = acc[dc][r] * linv[r];
        }
}

extern "C" void kernel_launch(void* const* d_in, const int* in_sizes, int n_in,
                              void* d_out, int out_size, void* d_ws, size_t ws_size,
                              hipStream_t stream) {
    const float* q = (const float*)d_in[0];
    const float* k = (const float*)d_in[1];
    const float* v = (const float*)d_in[2];
    float* o = (float*)d_out;
    const size_t need = (size_t)2 * 64 * 64 * 4096;  // K + V bf16 tile images
    if (ws_size >= need) {
        uint4* kimg = (uint4*)d_ws;
        uint4* vimg = kimg + (size_t)64 * 64 * 256;
        hipLaunchKernelGGL(prep_kv, dim3(8192), dim3(256), 0, stream, k, v, kimg, vimg);
        hipLaunchKernelGGL(fa_kernel, dim3(1024), dim3(256), 0, stream, q, kimg, vimg, o);
    } else {
        hipLaunchKernelGGL(fa_kernel_fb, dim3(2048), dim3(256), 0, stream, q, k, v, o);
    }
}